// Round 6
// baseline (7095.020 us; speedup 1.0000x reference)
//
#include <hip/hip_runtime.h>
#include <math.h>

// Problem constants
#define BB 64      // batch
#define SS 512     // seq
#define EE 256     // embed
#define HH 512     // hidden

// Distributed recurrence: 32 groups x 2 batches; each group = 8 blocks;
// block owns 64 outputs x 2 batches; its W-slice (64x512 f32) lives in
// registers (asm-pinned -- round-4's allocator remat demoted it otherwise).
// Blocks of a group exchange h each step via L2/IC.
//
// Round-6 sync: per-block FLAGS (128B-line padded, release-store + parallel
// acquire-poll by lanes 0..7) replace round-5's fetch_add counters -- all
// 128 blocks RMW'd the SAME 2 cache lines each step, serializing ~3-6us/step
// at the coherence point. Flags have zero RMW contention and one-way
// propagation. Grid widened 128->256 blocks (BPG 4->2, NGROUPS 16->32).
#define NGROUPS 32
#define GSLICES 8          // blocks per group
#define BPG 2              // batches per group
#define RECT 512           // threads per rec block

// ---------------------------------------------------------------------------

// W transpose: WT[j][i] = W[i][j], 512x512
__global__ void transpose512(const float* __restrict__ in, float* __restrict__ out) {
  __shared__ float tile[32][33];
  int bx = blockIdx.x * 32, by = blockIdx.y * 32;
  int x = threadIdx.x, y0 = threadIdx.y;  // block (32,8)
  for (int dy = 0; dy < 32; dy += 8)
    tile[y0 + dy][x] = in[(size_t)(by + y0 + dy) * HH + bx + x];
  __syncthreads();
  for (int dy = 0; dy < 32; dy += 8)
    out[(size_t)(bx + y0 + dy) * HH + by + x] = tile[x][y0 + dy];
}

// Tiled GEMM: C[m][n] = sum_k A[m][k] * Wn[n][k] + bias1[n] + bias2[n]
template <int K, bool GATHER>
__global__ __launch_bounds__(256) void xp_gemm(
    const float* __restrict__ Asrc, const int* __restrict__ xidx,
    const float* __restrict__ emb, const float* __restrict__ Wn,
    const float* __restrict__ bias1, const float* __restrict__ bias2,
    float* __restrict__ C) {
  const int tid = threadIdx.x;
  const int m0 = blockIdx.x * 64;
  const int n0 = blockIdx.y * 64;
  __shared__ alignas(16) float As[32][68];
  __shared__ alignas(16) float Bs[32][68];
  __shared__ int xs[64];
  if (GATHER) {
    if (tid < 64) xs[tid] = xidx[m0 + tid];
    __syncthreads();
  }
  float acc[4][4] = {};
  const int ty = tid >> 4, tx = tid & 15;
  const int row = tid >> 2;          // 0..63
  const int kc = (tid & 3) * 8;      // 0,8,16,24

  for (int k0 = 0; k0 < K; k0 += 32) {
    const float* ap;
    if (GATHER) ap = emb + (size_t)xs[row] * EE + (k0 + kc);
    else        ap = Asrc + (size_t)(m0 + row) * K + (k0 + kc);
    float4 av0 = *(const float4*)ap;
    float4 av1 = *(const float4*)(ap + 4);
    const float* bp = Wn + (size_t)(n0 + row) * K + (k0 + kc);
    float4 bv0 = *(const float4*)bp;
    float4 bv1 = *(const float4*)(bp + 4);
    __syncthreads();
    As[kc + 0][row] = av0.x; As[kc + 1][row] = av0.y;
    As[kc + 2][row] = av0.z; As[kc + 3][row] = av0.w;
    As[kc + 4][row] = av1.x; As[kc + 5][row] = av1.y;
    As[kc + 6][row] = av1.z; As[kc + 7][row] = av1.w;
    Bs[kc + 0][row] = bv0.x; Bs[kc + 1][row] = bv0.y;
    Bs[kc + 2][row] = bv0.z; Bs[kc + 3][row] = bv0.w;
    Bs[kc + 4][row] = bv1.x; Bs[kc + 5][row] = bv1.y;
    Bs[kc + 6][row] = bv1.z; Bs[kc + 7][row] = bv1.w;
    __syncthreads();
#pragma unroll 8
    for (int k = 0; k < 32; ++k) {
      float4 av = *(const float4*)&As[k][ty * 4];
      float4 bv = *(const float4*)&Bs[k][tx * 4];
      acc[0][0] += av.x * bv.x; acc[0][1] += av.x * bv.y;
      acc[0][2] += av.x * bv.z; acc[0][3] += av.x * bv.w;
      acc[1][0] += av.y * bv.x; acc[1][1] += av.y * bv.y;
      acc[1][2] += av.y * bv.z; acc[1][3] += av.y * bv.w;
      acc[2][0] += av.z * bv.x; acc[2][1] += av.z * bv.y;
      acc[2][2] += av.z * bv.z; acc[2][3] += av.z * bv.w;
      acc[3][0] += av.w * bv.x; acc[3][1] += av.w * bv.y;
      acc[3][2] += av.w * bv.z; acc[3][3] += av.w * bv.w;
    }
  }
  float bj[4];
#pragma unroll
  for (int j = 0; j < 4; ++j) {
    int n = n0 + tx * 4 + j;
    bj[j] = bias1[n] + bias2[n];
  }
#pragma unroll
  for (int i = 0; i < 4; ++i) {
    float4 cv = make_float4(acc[i][0] + bj[0], acc[i][1] + bj[1],
                            acc[i][2] + bj[2], acc[i][3] + bj[3]);
    *(float4*)&C[(size_t)(m0 + ty * 4 + i) * HH + n0 + tx * 4] = cv;
  }
}

// zero h-exchange buffers + flags (must run every launch: graph replays do
// not re-poison the workspace and flags are monotonic)
__global__ void init_sync(float* __restrict__ hbuf, unsigned* __restrict__ flags) {
  int i = blockIdx.x * 256 + threadIdx.x;
  if (i < 2 * NGROUPS * 2 * BPG * HH) hbuf[i] = 0.f;
  if (i < 2 * NGROUPS * GSLICES * 32) flags[i] = 0u;
}

__device__ __forceinline__ void fma4(float4& d, const float4 w, const float s) {
  d.x = __builtin_fmaf(w.x, s, d.x);
  d.y = __builtin_fmaf(w.y, s, d.y);
  d.z = __builtin_fmaf(w.z, s, d.z);
  d.w = __builtin_fmaf(w.w, s, d.w);
}

// Distributed recurrence.
// bid -> r = bid&7 (XCD-guess), k = bid>>3; slice = k&7, grp = (r<<2)|(k>>3).
// Thread (oo4 = tid&15, jg = tid>>4): outputs obase..obase+3
// (obase = slice*64 + oo4*4), j-range [jg*16, jg*16+16), both batches.
// wreg[j] = WT[jg*16+j][obase..+3] -- registers, loaded once, asm-pinned.
template <bool WRITE_OUT>
__global__ __launch_bounds__(RECT, 2) void rec_sync(
    const float* __restrict__ xp,     // [BB][SS][HH]
    const float* __restrict__ WT,     // [HH][HH] = W_hh^T
    float* __restrict__ outp,         // [BB][SS][HH] (layer 0)
    float* __restrict__ pooled,       // [BB][HH]     (layer 1)
    float* __restrict__ hbuf,         // [NGROUPS][2][BPG][HH]
    unsigned* __restrict__ flags) {   // [NGROUPS][GSLICES][32] (128B lines)
  const int tid = threadIdx.x;
  const int bid = blockIdx.x;
  const int r = bid & 7, k = bid >> 3;
  const int slice = k & 7;
  const int grp = (r << 2) | (k >> 3);
  const int oo4 = tid & 15;
  const int jg = tid >> 4;            // 0..31
  const int obase = slice * 64 + oo4 * 4;

  // ---- load W slice into registers (once); pin so the allocator cannot
  //      remat the loads back into the loop (round-4 failure mode) ----
  float4 wreg[16];
#pragma unroll
  for (int j = 0; j < 16; ++j)
    wreg[j] = *(const float4*)&WT[(size_t)(jg * 16 + j) * HH + obase];
#pragma unroll
  for (int j = 0; j < 16; ++j)
    asm volatile("" : "+v"(wreg[j].x), "+v"(wreg[j].y),
                      "+v"(wreg[j].z), "+v"(wreg[j].w));

  float* hb = hbuf + (size_t)grp * (2 * BPG * HH);
  unsigned* flg = flags + (size_t)grp * (GSLICES * 32);

  __shared__ float part[8][16][9];    // [wave][oo4][b*4+c], padded

  const int wave = tid >> 6, wl = tid & 63;
  const int fo = tid & 63;                 // finalize: output within slice
  const int fbb = (tid >> 6) & 1;          // finalize: batch (tid<128)
  const int fog = slice * 64 + fo;
  const size_t fxbase = (size_t)(grp * BPG + fbb) * (SS * HH) + fog;
  float pacc = 0.f;

  for (int t = 0; t < SS; ++t) {
    const int wp = t & 1, rp = wp ^ 1;
    float xv = 0.f;
    if (tid < 128) xv = xp[fxbase + (size_t)t * HH];  // waves 0-1 only

    // ---- read h_{t-1} (slot rp): 16-lane-broadcast global loads ----
    float4 hreg[BPG][4];
#pragma unroll
    for (int b = 0; b < BPG; ++b)
#pragma unroll
      for (int q = 0; q < 4; ++q)
        hreg[b][q] = *(const float4*)&hb[((size_t)rp * BPG + b) * HH + jg * 16 + q * 4];

    // ---- 128 FMAs, all operands in registers ----
    float4 acc[BPG] = {{0,0,0,0},{0,0,0,0}};
#pragma unroll
    for (int q = 0; q < 4; ++q) {
      float4 w0 = wreg[q * 4 + 0], w1 = wreg[q * 4 + 1];
      float4 w2 = wreg[q * 4 + 2], w3 = wreg[q * 4 + 3];
#pragma unroll
      for (int b = 0; b < BPG; ++b) {
        float4 hv = hreg[b][q];
        fma4(acc[b], w0, hv.x);
        fma4(acc[b], w1, hv.y);
        fma4(acc[b], w2, hv.z);
        fma4(acc[b], w3, hv.w);
      }
    }

    // ---- reduce over jg: 4 j-groups within wave via shfl ----
#pragma unroll
    for (int b = 0; b < BPG; ++b) {
      acc[b].x += __shfl_down(acc[b].x, 32); acc[b].y += __shfl_down(acc[b].y, 32);
      acc[b].z += __shfl_down(acc[b].z, 32); acc[b].w += __shfl_down(acc[b].w, 32);
      acc[b].x += __shfl_down(acc[b].x, 16); acc[b].y += __shfl_down(acc[b].y, 16);
      acc[b].z += __shfl_down(acc[b].z, 16); acc[b].w += __shfl_down(acc[b].w, 16);
    }
    if (wl < 16) {
#pragma unroll
      for (int b = 0; b < BPG; ++b) {
        part[wave][wl][b * 4 + 0] = acc[b].x;
        part[wave][wl][b * 4 + 1] = acc[b].y;
        part[wave][wl][b * 4 + 2] = acc[b].z;
        part[wave][wl][b * 4 + 3] = acc[b].w;
      }
    }
    __syncthreads();

    // ---- finalize: 8-wave reduce + tanh + publish h slice ----
    if (tid < 128) {
      float v = xv;
#pragma unroll
      for (int w = 0; w < 8; ++w) v += part[w][fo >> 2][fbb * 4 + (fo & 3)];
      float h = tanhf(v);
      hb[((size_t)wp * BPG + fbb) * HH + fog] = h;
      if (WRITE_OUT) outp[fxbase + (size_t)t * HH] = h;
      else pacc += h;
    }
    __syncthreads();   // each wave drains vmcnt: h stores done before release

    // ---- group barrier: per-block flag lines, no RMW contention ----
    if (tid == 0)
      __hip_atomic_store(&flg[slice * 32], (unsigned)(t + 1),
                         __ATOMIC_RELEASE, __HIP_MEMORY_SCOPE_AGENT);
    if (tid < GSLICES) {   // lanes 0..7 poll the 8 flags in parallel
      while (__hip_atomic_load(&flg[tid * 32], __ATOMIC_ACQUIRE,
                               __HIP_MEMORY_SCOPE_AGENT) < (unsigned)(t + 1)) { }
    }
    __syncthreads();
  }

  if (!WRITE_OUT && tid < 128)
    pooled[(size_t)(grp * BPG + fbb) * HH + fog] = pacc * (1.0f / SS);
}

// Final head: out[b][c] = sum_k pooled[b][k] * W_out[c][k] + b_out[c]
__global__ void out_kernel(const float* __restrict__ pooled,
                           const float* __restrict__ W_out,
                           const float* __restrict__ b_out,
                           float* __restrict__ out) {
  int tid = threadIdx.x;
  if (tid >= BB * 2) return;
  int b = tid >> 1, c = tid & 1;
  float acc = b_out[c];
  for (int k = 0; k < HH; ++k)
    acc += pooled[(size_t)b * HH + k] * W_out[(size_t)c * HH + k];
  out[(size_t)b * 2 + c] = acc;
}

extern "C" void kernel_launch(void* const* d_in, const int* in_sizes, int n_in,
                              void* d_out, int out_size, void* d_ws, size_t ws_size,
                              hipStream_t stream) {
  const int*   x     = (const int*)d_in[0];
  const float* emb   = (const float*)d_in[1];
  const float* W_ih0 = (const float*)d_in[2];
  const float* W_hh0 = (const float*)d_in[3];
  const float* b_ih0 = (const float*)d_in[4];
  const float* b_hh0 = (const float*)d_in[5];
  const float* W_ih1 = (const float*)d_in[6];
  const float* W_hh1 = (const float*)d_in[7];
  const float* b_ih1 = (const float*)d_in[8];
  const float* b_hh1 = (const float*)d_in[9];
  const float* W_out = (const float*)d_in[10];
  const float* b_out = (const float*)d_in[11];

  float* ws = (float*)d_ws;
  const size_t NBSH = (size_t)BB * SS * HH;  // 16777216
  const size_t HB   = (size_t)NGROUPS * 2 * BPG * HH;   // 65536 floats
  float* xp     = ws;                  // 64 MB (xp0, later xp1)
  float* out0   = ws + NBSH;           // 64 MB
  float* WT0    = ws + 2 * NBSH;       // 1 MB
  float* WT1    = WT0 + HH * HH;       // 1 MB
  float* pooled = WT1 + HH * HH;       // 128 KB
  float* hbuf0  = pooled + BB * HH;    // 256 KB
  float* hbuf1  = hbuf0 + HB;          // 256 KB
  unsigned* flags0 = (unsigned*)(hbuf1 + HB);            // 32 KB
  unsigned* flags1 = flags0 + NGROUPS * GSLICES * 32;    // 32 KB

  init_sync<<<512, 256, 0, stream>>>(hbuf0, flags0);

  dim3 tb(32, 8), tg(16, 16);
  transpose512<<<tg, tb, 0, stream>>>(W_hh0, WT0);
  transpose512<<<tg, tb, 0, stream>>>(W_hh1, WT1);

  dim3 gg(512, 8);
  xp_gemm<EE, true><<<gg, 256, 0, stream>>>(nullptr, x, emb, W_ih0, b_ih0, b_hh0, xp);
  rec_sync<true><<<NGROUPS * GSLICES, RECT, 0, stream>>>(
      xp, WT0, out0, nullptr, hbuf0, flags0);
  xp_gemm<HH, false><<<gg, 256, 0, stream>>>(out0, nullptr, nullptr, W_ih1, b_ih1, b_hh1, xp);
  rec_sync<false><<<NGROUPS * GSLICES, RECT, 0, stream>>>(
      xp, WT1, nullptr, pooled, hbuf1, flags1);
  out_kernel<<<1, 128, 0, stream>>>(pooled, W_out, b_out, (float*)d_out);
}

// Round 7
// 5028.013 us; speedup vs baseline: 1.4111x; 1.4111x over previous
//
#include <hip/hip_runtime.h>
#include <math.h>

// Problem constants
#define BB 64      // batch
#define SS 512     // seq
#define EE 256     // embed
#define HH 512     // hidden

// Distributed recurrence: 16 groups x 4 batches; each group = 8 blocks;
// block owns 64 outputs x 4 batches; W-slice (64x512 f32) in registers
// (asm-pinned; round-4's allocator remat demoted it otherwise). Blocks of a
// group exchange h each step via the IC with per-block padded flags.
//
// Round-7 sync protocol (round 6 regressed): poll with RELAXED agent loads
// (no buffer_inv per iteration -- round 6's acquire-poll invalidated the
// XCD L2 every ~50cyc, FETCH +22%, and got slower with more blocks), then
// ONE acquire fence per step after detection, then __syncthreads. Release
// flag store (one buffer_wbl2/step) pushes the h-slice to the IC.
#define NGROUPS 16
#define GSLICES 8          // blocks per group
#define BPG 4              // batches per group
#define RECT 512           // threads per rec block

// ---------------------------------------------------------------------------

// W transpose: WT[j][i] = W[i][j], 512x512
__global__ void transpose512(const float* __restrict__ in, float* __restrict__ out) {
  __shared__ float tile[32][33];
  int bx = blockIdx.x * 32, by = blockIdx.y * 32;
  int x = threadIdx.x, y0 = threadIdx.y;  // block (32,8)
  for (int dy = 0; dy < 32; dy += 8)
    tile[y0 + dy][x] = in[(size_t)(by + y0 + dy) * HH + bx + x];
  __syncthreads();
  for (int dy = 0; dy < 32; dy += 8)
    out[(size_t)(bx + y0 + dy) * HH + by + x] = tile[x][y0 + dy];
}

// Tiled GEMM: C[m][n] = sum_k A[m][k] * Wn[n][k] + bias1[n] + bias2[n]
template <int K, bool GATHER>
__global__ __launch_bounds__(256) void xp_gemm(
    const float* __restrict__ Asrc, const int* __restrict__ xidx,
    const float* __restrict__ emb, const float* __restrict__ Wn,
    const float* __restrict__ bias1, const float* __restrict__ bias2,
    float* __restrict__ C) {
  const int tid = threadIdx.x;
  const int m0 = blockIdx.x * 64;
  const int n0 = blockIdx.y * 64;
  __shared__ alignas(16) float As[32][68];
  __shared__ alignas(16) float Bs[32][68];
  __shared__ int xs[64];
  if (GATHER) {
    if (tid < 64) xs[tid] = xidx[m0 + tid];
    __syncthreads();
  }
  float acc[4][4] = {};
  const int ty = tid >> 4, tx = tid & 15;
  const int row = tid >> 2;          // 0..63
  const int kc = (tid & 3) * 8;      // 0,8,16,24

  for (int k0 = 0; k0 < K; k0 += 32) {
    const float* ap;
    if (GATHER) ap = emb + (size_t)xs[row] * EE + (k0 + kc);
    else        ap = Asrc + (size_t)(m0 + row) * K + (k0 + kc);
    float4 av0 = *(const float4*)ap;
    float4 av1 = *(const float4*)(ap + 4);
    const float* bp = Wn + (size_t)(n0 + row) * K + (k0 + kc);
    float4 bv0 = *(const float4*)bp;
    float4 bv1 = *(const float4*)(bp + 4);
    __syncthreads();
    As[kc + 0][row] = av0.x; As[kc + 1][row] = av0.y;
    As[kc + 2][row] = av0.z; As[kc + 3][row] = av0.w;
    As[kc + 4][row] = av1.x; As[kc + 5][row] = av1.y;
    As[kc + 6][row] = av1.z; As[kc + 7][row] = av1.w;
    Bs[kc + 0][row] = bv0.x; Bs[kc + 1][row] = bv0.y;
    Bs[kc + 2][row] = bv0.z; Bs[kc + 3][row] = bv0.w;
    Bs[kc + 4][row] = bv1.x; Bs[kc + 5][row] = bv1.y;
    Bs[kc + 6][row] = bv1.z; Bs[kc + 7][row] = bv1.w;
    __syncthreads();
#pragma unroll 8
    for (int k = 0; k < 32; ++k) {
      float4 av = *(const float4*)&As[k][ty * 4];
      float4 bv = *(const float4*)&Bs[k][tx * 4];
      acc[0][0] += av.x * bv.x; acc[0][1] += av.x * bv.y;
      acc[0][2] += av.x * bv.z; acc[0][3] += av.x * bv.w;
      acc[1][0] += av.y * bv.x; acc[1][1] += av.y * bv.y;
      acc[1][2] += av.y * bv.z; acc[1][3] += av.y * bv.w;
      acc[2][0] += av.z * bv.x; acc[2][1] += av.z * bv.y;
      acc[2][2] += av.z * bv.z; acc[2][3] += av.z * bv.w;
      acc[3][0] += av.w * bv.x; acc[3][1] += av.w * bv.y;
      acc[3][2] += av.w * bv.z; acc[3][3] += av.w * bv.w;
    }
  }
  float bj[4];
#pragma unroll
  for (int j = 0; j < 4; ++j) {
    int n = n0 + tx * 4 + j;
    bj[j] = bias1[n] + bias2[n];
  }
#pragma unroll
  for (int i = 0; i < 4; ++i) {
    float4 cv = make_float4(acc[i][0] + bj[0], acc[i][1] + bj[1],
                            acc[i][2] + bj[2], acc[i][3] + bj[3]);
    *(float4*)&C[(size_t)(m0 + ty * 4 + i) * HH + n0 + tx * 4] = cv;
  }
}

// zero h-exchange buffers + flags (must run every launch: graph replays do
// not re-poison the workspace and flags are monotonic)
__global__ void init_sync(float* __restrict__ hbuf, unsigned* __restrict__ flags) {
  int i = blockIdx.x * 256 + threadIdx.x;
  if (i < 2 * NGROUPS * 2 * BPG * HH) hbuf[i] = 0.f;
  if (i < 2 * NGROUPS * GSLICES * 32) flags[i] = 0u;
}

__device__ __forceinline__ void fma4(float4& d, const float4 w, const float s) {
  d.x = __builtin_fmaf(w.x, s, d.x);
  d.y = __builtin_fmaf(w.y, s, d.y);
  d.z = __builtin_fmaf(w.z, s, d.z);
  d.w = __builtin_fmaf(w.w, s, d.w);
}

// Distributed recurrence.
// bid -> r = bid&7 (XCD-guess), k = bid>>3; slice = k&7, grp = (r<<1)|(k>>3).
// Thread (oo4 = tid&15, jg = tid>>4): outputs obase..obase+3
// (obase = slice*64 + oo4*4), j-range [jg*16, jg*16+16), 4 batches.
// wreg[j] = WT[jg*16+j][obase..+3] -- registers, loaded once, asm-pinned.
template <bool WRITE_OUT>
__global__ __launch_bounds__(RECT, 2) void rec_sync(
    const float* __restrict__ xp,     // [BB][SS][HH]
    const float* __restrict__ WT,     // [HH][HH] = W_hh^T
    float* __restrict__ outp,         // [BB][SS][HH] (layer 0)
    float* __restrict__ pooled,       // [BB][HH]     (layer 1)
    float* __restrict__ hbuf,         // [NGROUPS][2][BPG][HH]
    unsigned* __restrict__ flags) {   // [NGROUPS][GSLICES][32] (128B lines)
  const int tid = threadIdx.x;
  const int bid = blockIdx.x;
  const int r = bid & 7, k = bid >> 3;
  const int slice = k & 7;
  const int grp = (r << 1) | (k >> 3);
  const int oo4 = tid & 15;
  const int jg = tid >> 4;            // 0..31
  const int obase = slice * 64 + oo4 * 4;

  // ---- load W slice into registers (once); pin so the allocator cannot
  //      remat the loads back into the loop (round-4 failure mode) ----
  float4 wreg[16];
#pragma unroll
  for (int j = 0; j < 16; ++j)
    wreg[j] = *(const float4*)&WT[(size_t)(jg * 16 + j) * HH + obase];
#pragma unroll
  for (int j = 0; j < 16; ++j)
    asm volatile("" : "+v"(wreg[j].x), "+v"(wreg[j].y),
                      "+v"(wreg[j].z), "+v"(wreg[j].w));

  float* hb = hbuf + (size_t)grp * (2 * BPG * HH);
  unsigned* flg = flags + (size_t)grp * (GSLICES * 32);

  __shared__ float part[8][16][17];   // [wave][oo4][b*4+c], padded

  const int wave = tid >> 6, wl = tid & 63;
  const int fo = tid & 63;                 // finalize: output within slice
  const int fbb = (tid >> 6) & 3;          // finalize: batch (tid<256)
  const int fog = slice * 64 + fo;
  const size_t fxbase = (size_t)(grp * BPG + fbb) * (SS * HH) + fog;
  float pacc = 0.f;

  for (int t = 0; t < SS; ++t) {
    const int wp = t & 1, rp = wp ^ 1;
    float xv = 0.f;
    if (tid < 256) xv = xp[fxbase + (size_t)t * HH];  // waves 0-3 only

    // ---- read h_{t-1} (slot rp): 16-lane-broadcast global loads ----
    float4 hreg[BPG][4];
#pragma unroll
    for (int b = 0; b < BPG; ++b)
#pragma unroll
      for (int q = 0; q < 4; ++q)
        hreg[b][q] = *(const float4*)&hb[((size_t)rp * BPG + b) * HH + jg * 16 + q * 4];

    // ---- 256 FMAs, all operands in registers ----
    float4 acc[BPG] = {{0,0,0,0},{0,0,0,0},{0,0,0,0},{0,0,0,0}};
#pragma unroll
    for (int q = 0; q < 4; ++q) {
      float4 w0 = wreg[q * 4 + 0], w1 = wreg[q * 4 + 1];
      float4 w2 = wreg[q * 4 + 2], w3 = wreg[q * 4 + 3];
#pragma unroll
      for (int b = 0; b < BPG; ++b) {
        float4 hv = hreg[b][q];
        fma4(acc[b], w0, hv.x);
        fma4(acc[b], w1, hv.y);
        fma4(acc[b], w2, hv.z);
        fma4(acc[b], w3, hv.w);
      }
    }

    // ---- reduce over jg: 4 j-groups within wave via shfl ----
#pragma unroll
    for (int b = 0; b < BPG; ++b) {
      acc[b].x += __shfl_down(acc[b].x, 32); acc[b].y += __shfl_down(acc[b].y, 32);
      acc[b].z += __shfl_down(acc[b].z, 32); acc[b].w += __shfl_down(acc[b].w, 32);
      acc[b].x += __shfl_down(acc[b].x, 16); acc[b].y += __shfl_down(acc[b].y, 16);
      acc[b].z += __shfl_down(acc[b].z, 16); acc[b].w += __shfl_down(acc[b].w, 16);
    }
    if (wl < 16) {
#pragma unroll
      for (int b = 0; b < BPG; ++b) {
        part[wave][wl][b * 4 + 0] = acc[b].x;
        part[wave][wl][b * 4 + 1] = acc[b].y;
        part[wave][wl][b * 4 + 2] = acc[b].z;
        part[wave][wl][b * 4 + 3] = acc[b].w;
      }
    }
    __syncthreads();

    // ---- finalize: 8-wave reduce + tanh + publish h slice ----
    if (tid < 256) {
      float v = xv;
#pragma unroll
      for (int w = 0; w < 8; ++w) v += part[w][fo >> 2][fbb * 4 + (fo & 3)];
      float h = tanhf(v);
      hb[((size_t)wp * BPG + fbb) * HH + fog] = h;
      if (WRITE_OUT) outp[fxbase + (size_t)t * HH] = h;
      else pacc += h;
    }
    __syncthreads();   // every wave drains vmcnt: h stores acked in L2

    // ---- group barrier ----
    // release: one buffer_wbl2/step pushes h to the IC, then flag store
    if (tid == 0)
      __hip_atomic_store(&flg[slice * 32], (unsigned)(t + 1),
                         __ATOMIC_RELEASE, __HIP_MEMORY_SCOPE_AGENT);
    // poll RELAXED (no per-iteration buffer_inv); lanes 0..7 in parallel
    if (tid < GSLICES) {
      while (__hip_atomic_load(&flg[tid * 32], __ATOMIC_RELAXED,
                               __HIP_MEMORY_SCOPE_AGENT) < (unsigned)(t + 1)) { }
    }
    // one acquire fence per step (single buffer_inv), then release the block
    if (wave == 0) __builtin_amdgcn_fence(__ATOMIC_ACQUIRE, "agent");
    __syncthreads();
  }

  if (!WRITE_OUT && tid < 256)
    pooled[(size_t)(grp * BPG + fbb) * HH + fog] = pacc * (1.0f / SS);
}

// Final head: out[b][c] = sum_k pooled[b][k] * W_out[c][k] + b_out[c]
__global__ void out_kernel(const float* __restrict__ pooled,
                           const float* __restrict__ W_out,
                           const float* __restrict__ b_out,
                           float* __restrict__ out) {
  int tid = threadIdx.x;
  if (tid >= BB * 2) return;
  int b = tid >> 1, c = tid & 1;
  float acc = b_out[c];
  for (int k = 0; k < HH; ++k)
    acc += pooled[(size_t)b * HH + k] * W_out[(size_t)c * HH + k];
  out[(size_t)b * 2 + c] = acc;
}

extern "C" void kernel_launch(void* const* d_in, const int* in_sizes, int n_in,
                              void* d_out, int out_size, void* d_ws, size_t ws_size,
                              hipStream_t stream) {
  const int*   x     = (const int*)d_in[0];
  const float* emb   = (const float*)d_in[1];
  const float* W_ih0 = (const float*)d_in[2];
  const float* W_hh0 = (const float*)d_in[3];
  const float* b_ih0 = (const float*)d_in[4];
  const float* b_hh0 = (const float*)d_in[5];
  const float* W_ih1 = (const float*)d_in[6];
  const float* W_hh1 = (const float*)d_in[7];
  const float* b_ih1 = (const float*)d_in[8];
  const float* b_hh1 = (const float*)d_in[9];
  const float* W_out = (const float*)d_in[10];
  const float* b_out = (const float*)d_in[11];

  float* ws = (float*)d_ws;
  const size_t NBSH = (size_t)BB * SS * HH;  // 16777216
  const size_t HB   = (size_t)NGROUPS * 2 * BPG * HH;   // 65536 floats
  float* xp     = ws;                  // 64 MB (xp0, later xp1)
  float* out0   = ws + NBSH;           // 64 MB
  float* WT0    = ws + 2 * NBSH;       // 1 MB
  float* WT1    = WT0 + HH * HH;       // 1 MB
  float* pooled = WT1 + HH * HH;       // 128 KB
  float* hbuf0  = pooled + BB * HH;    // 256 KB
  float* hbuf1  = hbuf0 + HB;          // 256 KB
  unsigned* flags0 = (unsigned*)(hbuf1 + HB);            // 16 KB
  unsigned* flags1 = flags0 + NGROUPS * GSLICES * 32;    // 16 KB

  init_sync<<<512, 256, 0, stream>>>(hbuf0, flags0);

  dim3 tb(32, 8), tg(16, 16);
  transpose512<<<tg, tb, 0, stream>>>(W_hh0, WT0);
  transpose512<<<tg, tb, 0, stream>>>(W_hh1, WT1);

  dim3 gg(512, 8);
  xp_gemm<EE, true><<<gg, 256, 0, stream>>>(nullptr, x, emb, W_ih0, b_ih0, b_hh0, xp);
  rec_sync<true><<<NGROUPS * GSLICES, RECT, 0, stream>>>(
      xp, WT0, out0, nullptr, hbuf0, flags0);
  xp_gemm<HH, false><<<gg, 256, 0, stream>>>(out0, nullptr, nullptr, W_ih1, b_ih1, b_hh1, xp);
  rec_sync<false><<<NGROUPS * GSLICES, RECT, 0, stream>>>(
      xp, WT1, nullptr, pooled, hbuf1, flags1);
  out_kernel<<<1, 128, 0, stream>>>(pooled, W_out, b_out, (float*)d_out);
}

// Round 9
// 3535.232 us; speedup vs baseline: 2.0069x; 1.4223x over previous
//
#include <hip/hip_runtime.h>
#include <math.h>

// Problem constants
#define BB 64      // batch
#define SS 512     // seq
#define EE 256     // embed
#define HH 512     // hidden

// Distributed recurrence: 16 groups x 4 batches; each group = 8 blocks;
// block owns 64 outputs x 4 batches; W-slice (64x512 f32) in registers
// (asm-pinned). Blocks exchange h each step DIRECTLY THROUGH THE IC:
// all h/flag traffic uses sc0 sc1 (bypass L1+L2) inline-asm ops, so NO
// buffer_wbl2 / buffer_inv cache maintenance is ever emitted (round 7's
// remaining per-step cost: release=wbl2, acquire-fence=inv, which also
// evicted the cached xp stream every step -> FETCH leak).
// Protocol per step: h stores sc0sc1 -> wave vmcnt(0) -> per-wave subflag
// store sc0sc1 -> lanes 0..31 poll the 32 subflags (sc0sc1 loads, no inv)
// -> __syncthreads -> batched h loads sc0sc1 (16x dwordx4, one vmcnt).
// Round-9 fix: global_load imm offset is 13-bit SIGNED (max +4095) -- b=2,3
// rows get their own base pointer instead of offsets 4096..6192.
#define NGROUPS 16
#define GSLICES 8          // blocks per group
#define BPG 4              // batches per group
#define RECT 512           // threads per rec block
#define FLW 4              // subflags per slice (one per finalize wave)

// ---------------------------------------------------------------------------

// W transpose: WT[j][i] = W[i][j], 512x512
__global__ void transpose512(const float* __restrict__ in, float* __restrict__ out) {
  __shared__ float tile[32][33];
  int bx = blockIdx.x * 32, by = blockIdx.y * 32;
  int x = threadIdx.x, y0 = threadIdx.y;  // block (32,8)
  for (int dy = 0; dy < 32; dy += 8)
    tile[y0 + dy][x] = in[(size_t)(by + y0 + dy) * HH + bx + x];
  __syncthreads();
  for (int dy = 0; dy < 32; dy += 8)
    out[(size_t)(bx + y0 + dy) * HH + by + x] = tile[x][y0 + dy];
}

// Tiled GEMM: C[m][n] = sum_k A[m][k] * Wn[n][k] + bias1[n] + bias2[n]
template <int K, bool GATHER>
__global__ __launch_bounds__(256) void xp_gemm(
    const float* __restrict__ Asrc, const int* __restrict__ xidx,
    const float* __restrict__ emb, const float* __restrict__ Wn,
    const float* __restrict__ bias1, const float* __restrict__ bias2,
    float* __restrict__ C) {
  const int tid = threadIdx.x;
  const int m0 = blockIdx.x * 64;
  const int n0 = blockIdx.y * 64;
  __shared__ alignas(16) float As[32][68];
  __shared__ alignas(16) float Bs[32][68];
  __shared__ int xs[64];
  if (GATHER) {
    if (tid < 64) xs[tid] = xidx[m0 + tid];
    __syncthreads();
  }
  float acc[4][4] = {};
  const int ty = tid >> 4, tx = tid & 15;
  const int row = tid >> 2;          // 0..63
  const int kc = (tid & 3) * 8;      // 0,8,16,24

  for (int k0 = 0; k0 < K; k0 += 32) {
    const float* ap;
    if (GATHER) ap = emb + (size_t)xs[row] * EE + (k0 + kc);
    else        ap = Asrc + (size_t)(m0 + row) * K + (k0 + kc);
    float4 av0 = *(const float4*)ap;
    float4 av1 = *(const float4*)(ap + 4);
    const float* bp = Wn + (size_t)(n0 + row) * K + (k0 + kc);
    float4 bv0 = *(const float4*)bp;
    float4 bv1 = *(const float4*)(bp + 4);
    __syncthreads();
    As[kc + 0][row] = av0.x; As[kc + 1][row] = av0.y;
    As[kc + 2][row] = av0.z; As[kc + 3][row] = av0.w;
    As[kc + 4][row] = av1.x; As[kc + 5][row] = av1.y;
    As[kc + 6][row] = av1.z; As[kc + 7][row] = av1.w;
    Bs[kc + 0][row] = bv0.x; Bs[kc + 1][row] = bv0.y;
    Bs[kc + 2][row] = bv0.z; Bs[kc + 3][row] = bv0.w;
    Bs[kc + 4][row] = bv1.x; Bs[kc + 5][row] = bv1.y;
    Bs[kc + 6][row] = bv1.z; Bs[kc + 7][row] = bv1.w;
    __syncthreads();
#pragma unroll 8
    for (int k = 0; k < 32; ++k) {
      float4 av = *(const float4*)&As[k][ty * 4];
      float4 bv = *(const float4*)&Bs[k][tx * 4];
      acc[0][0] += av.x * bv.x; acc[0][1] += av.x * bv.y;
      acc[0][2] += av.x * bv.z; acc[0][3] += av.x * bv.w;
      acc[1][0] += av.y * bv.x; acc[1][1] += av.y * bv.y;
      acc[1][2] += av.y * bv.z; acc[1][3] += av.y * bv.w;
      acc[2][0] += av.z * bv.x; acc[2][1] += av.z * bv.y;
      acc[2][2] += av.z * bv.z; acc[2][3] += av.z * bv.w;
      acc[3][0] += av.w * bv.x; acc[3][1] += av.w * bv.y;
      acc[3][2] += av.w * bv.z; acc[3][3] += av.w * bv.w;
    }
  }
  float bj[4];
#pragma unroll
  for (int j = 0; j < 4; ++j) {
    int n = n0 + tx * 4 + j;
    bj[j] = bias1[n] + bias2[n];
  }
#pragma unroll
  for (int i = 0; i < 4; ++i) {
    float4 cv = make_float4(acc[i][0] + bj[0], acc[i][1] + bj[1],
                            acc[i][2] + bj[2], acc[i][3] + bj[3]);
    *(float4*)&C[(size_t)(m0 + ty * 4 + i) * HH + n0 + tx * 4] = cv;
  }
}

// Initialize h-exchange buffers + flags AT THE IC (system-scope relaxed
// stores emit sc0 sc1 -- the IC copy must be the valid one since rec only
// reads/writes these lines with cache-bypass ops). Runs every launch.
__global__ void init_sync(float* __restrict__ hbuf, unsigned* __restrict__ flags) {
  int i = blockIdx.x * 256 + threadIdx.x;
  if (i < 2 * NGROUPS * 2 * BPG * HH)
    __hip_atomic_store(&hbuf[i], 0.f, __ATOMIC_RELAXED, __HIP_MEMORY_SCOPE_SYSTEM);
  if (i < 2 * NGROUPS * GSLICES * FLW * 32)
    __hip_atomic_store(&flags[i], 0u, __ATOMIC_RELAXED, __HIP_MEMORY_SCOPE_SYSTEM);
}

__device__ __forceinline__ void fma4(float4& d, const float4 w, const float s) {
  d.x = __builtin_fmaf(w.x, s, d.x);
  d.y = __builtin_fmaf(w.y, s, d.y);
  d.z = __builtin_fmaf(w.z, s, d.z);
  d.w = __builtin_fmaf(w.w, s, d.w);
}

// Distributed recurrence.
// bid -> r = bid&7, k = bid>>3; slice = k&7, grp = (r<<1)|(k>>3).
// Thread (oo4 = tid&15, jg = tid>>4): outputs obase..obase+3
// (obase = slice*64 + oo4*4), j-range [jg*16, jg*16+16), 4 batches.
template <bool WRITE_OUT>
__global__ __launch_bounds__(RECT, 2) void rec_sync(
    const float* __restrict__ xp,     // [BB][SS][HH]
    const float* __restrict__ WT,     // [HH][HH] = W_hh^T
    float* __restrict__ outp,         // [BB][SS][HH] (layer 0)
    float* __restrict__ pooled,       // [BB][HH]     (layer 1)
    float* __restrict__ hbuf,         // [NGROUPS][2][BPG][HH]  (IC-only lines)
    unsigned* __restrict__ flags) {   // [NGROUPS][GSLICES][FLW][32]
  const int tid = threadIdx.x;
  const int bid = blockIdx.x;
  const int r = bid & 7, k = bid >> 3;
  const int slice = k & 7;
  const int grp = (r << 1) | (k >> 3);
  const int oo4 = tid & 15;
  const int jg = tid >> 4;            // 0..31
  const int obase = slice * 64 + oo4 * 4;

  // ---- load W slice into registers (once); pin against remat ----
  float4 wreg[16];
#pragma unroll
  for (int j = 0; j < 16; ++j)
    wreg[j] = *(const float4*)&WT[(size_t)(jg * 16 + j) * HH + obase];
#pragma unroll
  for (int j = 0; j < 16; ++j)
    asm volatile("" : "+v"(wreg[j].x), "+v"(wreg[j].y),
                      "+v"(wreg[j].z), "+v"(wreg[j].w));

  float* hbase = hbuf + (size_t)grp * (2 * BPG * HH);
  unsigned* flg = flags + (size_t)grp * (GSLICES * FLW * 32);

  __shared__ float part[8][16][17];   // [wave][oo4][b*4+c], padded

  const int wave = tid >> 6, wl = tid & 63;
  const int fo = tid & 63;                 // finalize: output within slice
  const int fbb = (tid >> 6) & 3;          // finalize: batch (tid<256)
  const int fog = slice * 64 + fo;
  const size_t fxbase = (size_t)(grp * BPG + fbb) * (SS * HH) + fog;
  float pacc = 0.f;

  for (int t = 0; t < SS; ++t) {
    const int wp = t & 1, rp = wp ^ 1;
    float xv = 0.f;
    if (tid < 256) xv = xp[fxbase + (size_t)t * HH];  // cached load, overlaps

    // ---- read h_{t-1} (slot rp) straight from the IC: 16x dwordx4 sc0sc1.
    //      Imm offset is 13-bit signed (max +4095): use 2 base pointers,
    //      hp0 for b=0,1 (offsets 0..2096) and hp2 for b=2,3. ----
    float4 hr[4][4];
    {
      const float* hp0 = hbase + (size_t)rp * (BPG * HH) + jg * 16;
      const float* hp2 = hp0 + 2 * HH;   // +4096 bytes
      asm volatile(
        "global_load_dwordx4 %0, %4, off sc0 sc1\n\t"
        "global_load_dwordx4 %1, %4, off offset:16 sc0 sc1\n\t"
        "global_load_dwordx4 %2, %4, off offset:32 sc0 sc1\n\t"
        "global_load_dwordx4 %3, %4, off offset:48 sc0 sc1"
        : "=&v"(hr[0][0]), "=&v"(hr[0][1]), "=&v"(hr[0][2]), "=&v"(hr[0][3])
        : "v"(hp0));
      asm volatile(
        "global_load_dwordx4 %0, %4, off offset:2048 sc0 sc1\n\t"
        "global_load_dwordx4 %1, %4, off offset:2064 sc0 sc1\n\t"
        "global_load_dwordx4 %2, %4, off offset:2080 sc0 sc1\n\t"
        "global_load_dwordx4 %3, %4, off offset:2096 sc0 sc1"
        : "=&v"(hr[1][0]), "=&v"(hr[1][1]), "=&v"(hr[1][2]), "=&v"(hr[1][3])
        : "v"(hp0));
      asm volatile(
        "global_load_dwordx4 %0, %4, off sc0 sc1\n\t"
        "global_load_dwordx4 %1, %4, off offset:16 sc0 sc1\n\t"
        "global_load_dwordx4 %2, %4, off offset:32 sc0 sc1\n\t"
        "global_load_dwordx4 %3, %4, off offset:48 sc0 sc1"
        : "=&v"(hr[2][0]), "=&v"(hr[2][1]), "=&v"(hr[2][2]), "=&v"(hr[2][3])
        : "v"(hp2));
      asm volatile(
        "global_load_dwordx4 %0, %4, off offset:2048 sc0 sc1\n\t"
        "global_load_dwordx4 %1, %4, off offset:2064 sc0 sc1\n\t"
        "global_load_dwordx4 %2, %4, off offset:2080 sc0 sc1\n\t"
        "global_load_dwordx4 %3, %4, off offset:2096 sc0 sc1"
        : "=&v"(hr[3][0]), "=&v"(hr[3][1]), "=&v"(hr[3][2]), "=&v"(hr[3][3])
        : "v"(hp2));
    }
    asm volatile("s_waitcnt vmcnt(0)" ::: "memory");
    __builtin_amdgcn_sched_barrier(0);   // rule #18: keep consumers below

    // ---- 256 FMAs, all operands in registers ----
    float4 acc[BPG] = {{0,0,0,0},{0,0,0,0},{0,0,0,0},{0,0,0,0}};
#pragma unroll
    for (int q = 0; q < 4; ++q) {
      float4 w0 = wreg[q * 4 + 0], w1 = wreg[q * 4 + 1];
      float4 w2 = wreg[q * 4 + 2], w3 = wreg[q * 4 + 3];
#pragma unroll
      for (int b = 0; b < BPG; ++b) {
        float4 hv = hr[b][q];
        fma4(acc[b], w0, hv.x);
        fma4(acc[b], w1, hv.y);
        fma4(acc[b], w2, hv.z);
        fma4(acc[b], w3, hv.w);
      }
    }

    // ---- reduce over jg: 4 j-groups within wave via shfl ----
#pragma unroll
    for (int b = 0; b < BPG; ++b) {
      acc[b].x += __shfl_down(acc[b].x, 32); acc[b].y += __shfl_down(acc[b].y, 32);
      acc[b].z += __shfl_down(acc[b].z, 32); acc[b].w += __shfl_down(acc[b].w, 32);
      acc[b].x += __shfl_down(acc[b].x, 16); acc[b].y += __shfl_down(acc[b].y, 16);
      acc[b].z += __shfl_down(acc[b].z, 16); acc[b].w += __shfl_down(acc[b].w, 16);
    }
    if (wl < 16) {
#pragma unroll
      for (int b = 0; b < BPG; ++b) {
        part[wave][wl][b * 4 + 0] = acc[b].x;
        part[wave][wl][b * 4 + 1] = acc[b].y;
        part[wave][wl][b * 4 + 2] = acc[b].z;
        part[wave][wl][b * 4 + 3] = acc[b].w;
      }
    }
    __syncthreads();

    // ---- finalize (waves 0-3): reduce + tanh + publish h to IC ----
    if (tid < 256) {
      float v = xv;
#pragma unroll
      for (int w = 0; w < 8; ++w) v += part[w][fo >> 2][fbb * 4 + (fo & 3)];
      float h = tanhf(v);
      float* hst = hbase + ((size_t)wp * BPG + fbb) * HH + fog;
      asm volatile("global_store_dword %0, %1, off sc0 sc1"
                   :: "v"(hst), "v"(h) : "memory");
      if (WRITE_OUT) outp[fxbase + (size_t)t * HH] = h;
      else pacc += h;
      asm volatile("s_waitcnt vmcnt(0)" ::: "memory");  // h durable at IC
      if (wl == 0) {                                    // per-wave subflag
        unsigned tp1 = (unsigned)(t + 1);
        unsigned* sf = flg + ((slice << 2) + wave) * 32;
        asm volatile("global_store_dword %0, %1, off sc0 sc1"
                     :: "v"(sf), "v"(tp1) : "memory");
      }
    }

    // ---- poll all 32 subflags (8 slices x 4 waves), lanes 0..31 ----
    if (tid < 32) {
      const unsigned tp1 = (unsigned)(t + 1);
      unsigned* fp = flg + tid * 32;
      unsigned v;
      do {
        asm volatile("global_load_dword %0, %1, off sc0 sc1\n\t"
                     "s_waitcnt vmcnt(0)"
                     : "=v"(v) : "v"(fp) : "memory");
      } while (v < tp1);
    }
    __syncthreads();   // releases all waves into step t+1
  }

  if (!WRITE_OUT && tid < 256)
    pooled[(size_t)(grp * BPG + fbb) * HH + fog] = pacc * (1.0f / SS);
}

// Final head: out[b][c] = sum_k pooled[b][k] * W_out[c][k] + b_out[c]
__global__ void out_kernel(const float* __restrict__ pooled,
                           const float* __restrict__ W_out,
                           const float* __restrict__ b_out,
                           float* __restrict__ out) {
  int tid = threadIdx.x;
  if (tid >= BB * 2) return;
  int b = tid >> 1, c = tid & 1;
  float acc = b_out[c];
  for (int k = 0; k < HH; ++k)
    acc += pooled[(size_t)b * HH + k] * W_out[(size_t)c * HH + k];
  out[(size_t)b * 2 + c] = acc;
}

extern "C" void kernel_launch(void* const* d_in, const int* in_sizes, int n_in,
                              void* d_out, int out_size, void* d_ws, size_t ws_size,
                              hipStream_t stream) {
  const int*   x     = (const int*)d_in[0];
  const float* emb   = (const float*)d_in[1];
  const float* W_ih0 = (const float*)d_in[2];
  const float* W_hh0 = (const float*)d_in[3];
  const float* b_ih0 = (const float*)d_in[4];
  const float* b_hh0 = (const float*)d_in[5];
  const float* W_ih1 = (const float*)d_in[6];
  const float* W_hh1 = (const float*)d_in[7];
  const float* b_ih1 = (const float*)d_in[8];
  const float* b_hh1 = (const float*)d_in[9];
  const float* W_out = (const float*)d_in[10];
  const float* b_out = (const float*)d_in[11];

  float* ws = (float*)d_ws;
  const size_t NBSH = (size_t)BB * SS * HH;  // 16777216
  const size_t HB   = (size_t)NGROUPS * 2 * BPG * HH;        // 65536 floats
  const size_t FL   = (size_t)NGROUPS * GSLICES * FLW * 32;  // 16384 u32
  float* xp     = ws;                  // 64 MB (xp0, later xp1)
  float* out0   = ws + NBSH;           // 64 MB
  float* WT0    = ws + 2 * NBSH;       // 1 MB
  float* WT1    = WT0 + HH * HH;       // 1 MB
  float* pooled = WT1 + HH * HH;       // 128 KB
  float* hbuf0  = pooled + BB * HH;    // 256 KB
  float* hbuf1  = hbuf0 + HB;          // 256 KB
  unsigned* flags0 = (unsigned*)(hbuf1 + HB);  // 64 KB
  unsigned* flags1 = flags0 + FL;              // 64 KB

  init_sync<<<512, 256, 0, stream>>>(hbuf0, flags0);

  dim3 tb(32, 8), tg(16, 16);
  transpose512<<<tg, tb, 0, stream>>>(W_hh0, WT0);
  transpose512<<<tg, tb, 0, stream>>>(W_hh1, WT1);

  dim3 gg(512, 8);
  xp_gemm<EE, true><<<gg, 256, 0, stream>>>(nullptr, x, emb, W_ih0, b_ih0, b_hh0, xp);
  rec_sync<true><<<NGROUPS * GSLICES, RECT, 0, stream>>>(
      xp, WT0, out0, nullptr, hbuf0, flags0);
  xp_gemm<HH, false><<<gg, 256, 0, stream>>>(out0, nullptr, nullptr, W_ih1, b_ih1, b_hh1, xp);
  rec_sync<false><<<NGROUPS * GSLICES, RECT, 0, stream>>>(
      xp, WT1, nullptr, pooled, hbuf1, flags1);
  out_kernel<<<1, 128, 0, stream>>>(pooled, W_out, b_out, (float*)d_out);
}

// Round 10
// 2146.388 us; speedup vs baseline: 3.3056x; 1.6471x over previous
//
#include <hip/hip_runtime.h>
#include <math.h>

// Problem constants
#define BB 64      // batch
#define SS 512     // seq
#define EE 256     // embed
#define HH 512     // hidden

// Round-10: FUSED two-layer pipelined recurrence.
// 16 groups x 4 batches; each group = 16 blocks (8 layer-0 slices + 8
// layer-1 slices), all lockstep on one 64-subflag barrier per step.
// L0 block: h0_s = tanh(xp0[s] + W_hh0 h0_{s-1})          (W_hh0^T in regs)
// L1 block: h1_{s-1} = tanh(b + W_ih1 h0_{s-1} + W_hh1 h1_{s-2})
//           (BOTH W_ih1^T and W_hh1^T slices in regs -- GEMM1 and the
//            out0/xp1 round trip are eliminated; serial chain 1024 -> 513
//            barrier steps). L1 lags L0 by one step; 2 h-slots suffice
//            under the lockstep barrier. Exchange stays IC-direct (sc0 sc1,
//            round-9 protocol: store -> vmcnt -> subflag -> relaxed poll).
#define NGROUPS 16
#define GSLICES 8          // slices per layer per group
#define LBLK 16            // blocks per group (2 layers x 8 slices)
#define BPG 4              // batches per group
#define RECT 512           // threads per rec block

// ---------------------------------------------------------------------------

// W transpose: WT[j][i] = W[i][j], 512x512
__global__ void transpose512(const float* __restrict__ in, float* __restrict__ out) {
  __shared__ float tile[32][33];
  int bx = blockIdx.x * 32, by = blockIdx.y * 32;
  int x = threadIdx.x, y0 = threadIdx.y;  // block (32,8)
  for (int dy = 0; dy < 32; dy += 8)
    tile[y0 + dy][x] = in[(size_t)(by + y0 + dy) * HH + bx + x];
  __syncthreads();
  for (int dy = 0; dy < 32; dy += 8)
    out[(size_t)(bx + y0 + dy) * HH + by + x] = tile[x][y0 + dy];
}

// Tiled GEMM with gather: C[m][n] = sum_k emb[x[m]][k] * Wn[n][k] + b1[n]+b2[n]
template <int K, bool GATHER>
__global__ __launch_bounds__(256) void xp_gemm(
    const float* __restrict__ Asrc, const int* __restrict__ xidx,
    const float* __restrict__ emb, const float* __restrict__ Wn,
    const float* __restrict__ bias1, const float* __restrict__ bias2,
    float* __restrict__ C) {
  const int tid = threadIdx.x;
  const int m0 = blockIdx.x * 64;
  const int n0 = blockIdx.y * 64;
  __shared__ alignas(16) float As[32][68];
  __shared__ alignas(16) float Bs[32][68];
  __shared__ int xs[64];
  if (GATHER) {
    if (tid < 64) xs[tid] = xidx[m0 + tid];
    __syncthreads();
  }
  float acc[4][4] = {};
  const int ty = tid >> 4, tx = tid & 15;
  const int row = tid >> 2;          // 0..63
  const int kc = (tid & 3) * 8;      // 0,8,16,24

  for (int k0 = 0; k0 < K; k0 += 32) {
    const float* ap;
    if (GATHER) ap = emb + (size_t)xs[row] * EE + (k0 + kc);
    else        ap = Asrc + (size_t)(m0 + row) * K + (k0 + kc);
    float4 av0 = *(const float4*)ap;
    float4 av1 = *(const float4*)(ap + 4);
    const float* bp = Wn + (size_t)(n0 + row) * K + (k0 + kc);
    float4 bv0 = *(const float4*)bp;
    float4 bv1 = *(const float4*)(bp + 4);
    __syncthreads();
    As[kc + 0][row] = av0.x; As[kc + 1][row] = av0.y;
    As[kc + 2][row] = av0.z; As[kc + 3][row] = av0.w;
    As[kc + 4][row] = av1.x; As[kc + 5][row] = av1.y;
    As[kc + 6][row] = av1.z; As[kc + 7][row] = av1.w;
    Bs[kc + 0][row] = bv0.x; Bs[kc + 1][row] = bv0.y;
    Bs[kc + 2][row] = bv0.z; Bs[kc + 3][row] = bv0.w;
    Bs[kc + 4][row] = bv1.x; Bs[kc + 5][row] = bv1.y;
    Bs[kc + 6][row] = bv1.z; Bs[kc + 7][row] = bv1.w;
    __syncthreads();
#pragma unroll 8
    for (int k = 0; k < 32; ++k) {
      float4 av = *(const float4*)&As[k][ty * 4];
      float4 bv = *(const float4*)&Bs[k][tx * 4];
      acc[0][0] += av.x * bv.x; acc[0][1] += av.x * bv.y;
      acc[0][2] += av.x * bv.z; acc[0][3] += av.x * bv.w;
      acc[1][0] += av.y * bv.x; acc[1][1] += av.y * bv.y;
      acc[1][2] += av.y * bv.z; acc[1][3] += av.y * bv.w;
      acc[2][0] += av.z * bv.x; acc[2][1] += av.z * bv.y;
      acc[2][2] += av.z * bv.z; acc[2][3] += av.z * bv.w;
      acc[3][0] += av.w * bv.x; acc[3][1] += av.w * bv.y;
      acc[3][2] += av.w * bv.z; acc[3][3] += av.w * bv.w;
    }
  }
  float bj[4];
#pragma unroll
  for (int j = 0; j < 4; ++j) {
    int n = n0 + tx * 4 + j;
    bj[j] = bias1[n] + bias2[n];
  }
#pragma unroll
  for (int i = 0; i < 4; ++i) {
    float4 cv = make_float4(acc[i][0] + bj[0], acc[i][1] + bj[1],
                            acc[i][2] + bj[2], acc[i][3] + bj[3]);
    *(float4*)&C[(size_t)(m0 + ty * 4 + i) * HH + n0 + tx * 4] = cv;
  }
}

// Initialize h-exchange buffers + flags AT THE IC (system-scope stores emit
// sc0 sc1 -- rec only touches these lines cache-bypassed). Every launch.
__global__ void init_sync(float* __restrict__ h0b, float* __restrict__ h1b,
                          unsigned* __restrict__ flags) {
  int i = blockIdx.x * 256 + threadIdx.x;
  if (i < NGROUPS * 2 * BPG * HH) {
    __hip_atomic_store(&h0b[i], 0.f, __ATOMIC_RELAXED, __HIP_MEMORY_SCOPE_SYSTEM);
    __hip_atomic_store(&h1b[i], 0.f, __ATOMIC_RELAXED, __HIP_MEMORY_SCOPE_SYSTEM);
  }
  if (i < NGROUPS * LBLK * 4 * 32)
    __hip_atomic_store(&flags[i], 0u, __ATOMIC_RELAXED, __HIP_MEMORY_SCOPE_SYSTEM);
}

__device__ __forceinline__ void fma4(float4& d, const float4 w, const float s) {
  d.x = __builtin_fmaf(w.x, s, d.x);
  d.y = __builtin_fmaf(w.y, s, d.y);
  d.z = __builtin_fmaf(w.z, s, d.z);
  d.w = __builtin_fmaf(w.w, s, d.w);
}

// 16x dwordx4 sc0 sc1 loads of one 4-batch h slot (jg-chunk). Imm offset is
// 13-bit signed (max +4095): two base pointers. No wait inside.
__device__ __forceinline__ void ld_h16(float4 hr[4][4], const float* hp0) {
  const float* hp2 = hp0 + 2 * HH;   // +4096 bytes
  asm volatile(
    "global_load_dwordx4 %0, %4, off sc0 sc1\n\t"
    "global_load_dwordx4 %1, %4, off offset:16 sc0 sc1\n\t"
    "global_load_dwordx4 %2, %4, off offset:32 sc0 sc1\n\t"
    "global_load_dwordx4 %3, %4, off offset:48 sc0 sc1"
    : "=&v"(hr[0][0]), "=&v"(hr[0][1]), "=&v"(hr[0][2]), "=&v"(hr[0][3])
    : "v"(hp0));
  asm volatile(
    "global_load_dwordx4 %0, %4, off offset:2048 sc0 sc1\n\t"
    "global_load_dwordx4 %1, %4, off offset:2064 sc0 sc1\n\t"
    "global_load_dwordx4 %2, %4, off offset:2080 sc0 sc1\n\t"
    "global_load_dwordx4 %3, %4, off offset:2096 sc0 sc1"
    : "=&v"(hr[1][0]), "=&v"(hr[1][1]), "=&v"(hr[1][2]), "=&v"(hr[1][3])
    : "v"(hp0));
  asm volatile(
    "global_load_dwordx4 %0, %4, off sc0 sc1\n\t"
    "global_load_dwordx4 %1, %4, off offset:16 sc0 sc1\n\t"
    "global_load_dwordx4 %2, %4, off offset:32 sc0 sc1\n\t"
    "global_load_dwordx4 %3, %4, off offset:48 sc0 sc1"
    : "=&v"(hr[2][0]), "=&v"(hr[2][1]), "=&v"(hr[2][2]), "=&v"(hr[2][3])
    : "v"(hp2));
  asm volatile(
    "global_load_dwordx4 %0, %4, off offset:2048 sc0 sc1\n\t"
    "global_load_dwordx4 %1, %4, off offset:2064 sc0 sc1\n\t"
    "global_load_dwordx4 %2, %4, off offset:2080 sc0 sc1\n\t"
    "global_load_dwordx4 %3, %4, off offset:2096 sc0 sc1"
    : "=&v"(hr[3][0]), "=&v"(hr[3][1]), "=&v"(hr[3][2]), "=&v"(hr[3][3])
    : "v"(hp2));
}

__device__ __forceinline__ void fma_mv(float4 acc[4], const float4 wreg[16],
                                       const float4 hr[4][4]) {
#pragma unroll
  for (int q = 0; q < 4; ++q) {
    float4 w0 = wreg[q * 4 + 0], w1 = wreg[q * 4 + 1];
    float4 w2 = wreg[q * 4 + 2], w3 = wreg[q * 4 + 3];
#pragma unroll
    for (int b = 0; b < 4; ++b) {
      float4 hv = hr[b][q];
      fma4(acc[b], w0, hv.x);
      fma4(acc[b], w1, hv.y);
      fma4(acc[b], w2, hv.z);
      fma4(acc[b], w3, hv.w);
    }
  }
}

// Fused 2-layer recurrence. bid: grp = bid&15, role = bid>>4 (0..7 = L0
// slices, 8..15 = L1 slices). Thread (oo4=tid&15, jg=tid>>4): outputs
// obase..obase+3, j-range [jg*16,+16), 4 batches.
__global__ __launch_bounds__(RECT, 2) void rec_fused(
    const float* __restrict__ xp,      // [BB][SS][HH] (layer-0 input proj)
    const float* __restrict__ WThh0,   // [HH][HH]
    const float* __restrict__ WTih1,   // [HH][HH]
    const float* __restrict__ WThh1,   // [HH][HH]
    const float* __restrict__ b_ih1,
    const float* __restrict__ b_hh1,
    float* __restrict__ pooled,        // [BB][HH]
    float* __restrict__ h0b,           // [NGROUPS][2][BPG][HH] (IC lines)
    float* __restrict__ h1b,           // [NGROUPS][2][BPG][HH]
    unsigned* __restrict__ flags) {    // [NGROUPS][LBLK*4][32]
  const int tid = threadIdx.x;
  const int bid = blockIdx.x;
  const int grp = bid & 15;
  const int role = bid >> 4;          // 0..15
  const bool isL1 = role >= GSLICES;
  const int slice = role & 7;
  const int oo4 = tid & 15;
  const int jg = tid >> 4;            // 0..31
  const int obase = slice * 64 + oo4 * 4;

  // ---- weights into registers (once); pin against remat (round-4 lesson) --
  float4 wregA[16], wregB[16];
  {
    const float* wb = isL1 ? WThh1 : WThh0;
#pragma unroll
    for (int j = 0; j < 16; ++j)
      wregB[j] = *(const float4*)&wb[(size_t)(jg * 16 + j) * HH + obase];
#pragma unroll
    for (int j = 0; j < 16; ++j)
      asm volatile("" : "+v"(wregB[j].x), "+v"(wregB[j].y),
                        "+v"(wregB[j].z), "+v"(wregB[j].w));
  }
  if (isL1) {
#pragma unroll
    for (int j = 0; j < 16; ++j)
      wregA[j] = *(const float4*)&WTih1[(size_t)(jg * 16 + j) * HH + obase];
#pragma unroll
    for (int j = 0; j < 16; ++j)
      asm volatile("" : "+v"(wregA[j].x), "+v"(wregA[j].y),
                        "+v"(wregA[j].z), "+v"(wregA[j].w));
  }

  float* h0g = h0b + (size_t)grp * (2 * BPG * HH);
  float* h1g = h1b + (size_t)grp * (2 * BPG * HH);
  unsigned* flg = flags + (size_t)grp * (LBLK * 4 * 32);

  __shared__ float part[8][16][17];   // [wave][oo4][b*4+c], padded

  const int wave = tid >> 6, wl = tid & 63;
  const int fo = tid & 63;                 // finalize: output within slice
  const int fbb = (tid >> 6) & 3;          // finalize: batch (tid<256)
  const int fog = slice * 64 + fo;
  const size_t fxbase = (size_t)(grp * BPG + fbb) * (SS * HH) + fog;
  float pacc = 0.f;
  float bs = 0.f;
  if (tid < 256) bs = b_ih1[fog] + b_hh1[fog];   // L1 bias sum (L0: unused)

  for (int s = 0; s < SS; ++s) {
    const bool doC = (!isL1) || (s >= 1);
    float4 acc[BPG] = {{0,0,0,0},{0,0,0,0},{0,0,0,0},{0,0,0,0}};
    float xv = 0.f;
    if (doC) {
      float4 hr[4][4];
      if (!isL1) {
        if (tid < 256) xv = xp[fxbase + (size_t)s * HH];   // cached
        ld_h16(hr, h0g + (size_t)((s + 1) & 1) * (BPG * HH) + jg * 16);
        asm volatile("s_waitcnt vmcnt(0)" ::: "memory");
        __builtin_amdgcn_sched_barrier(0);
        fma_mv(acc, wregB, hr);
      } else {
        const int t1 = s - 1;
        // phase A: W_ih1 x h0_{t1}
        ld_h16(hr, h0g + (size_t)(t1 & 1) * (BPG * HH) + jg * 16);
        asm volatile("s_waitcnt vmcnt(0)" ::: "memory");
        __builtin_amdgcn_sched_barrier(0);
        fma_mv(acc, wregA, hr);
        // phase B: + W_hh1 x h1_{t1-1}   (hr reused -> sequential, low VGPR)
        ld_h16(hr, h1g + (size_t)((t1 + 1) & 1) * (BPG * HH) + jg * 16);
        asm volatile("s_waitcnt vmcnt(0)" ::: "memory");
        __builtin_amdgcn_sched_barrier(0);
        fma_mv(acc, wregB, hr);
      }
      // reduce over jg: 4 j-groups within wave via shfl
#pragma unroll
      for (int b = 0; b < BPG; ++b) {
        acc[b].x += __shfl_down(acc[b].x, 32); acc[b].y += __shfl_down(acc[b].y, 32);
        acc[b].z += __shfl_down(acc[b].z, 32); acc[b].w += __shfl_down(acc[b].w, 32);
        acc[b].x += __shfl_down(acc[b].x, 16); acc[b].y += __shfl_down(acc[b].y, 16);
        acc[b].z += __shfl_down(acc[b].z, 16); acc[b].w += __shfl_down(acc[b].w, 16);
      }
      if (wl < 16) {
#pragma unroll
        for (int b = 0; b < BPG; ++b) {
          part[wave][wl][b * 4 + 0] = acc[b].x;
          part[wave][wl][b * 4 + 1] = acc[b].y;
          part[wave][wl][b * 4 + 2] = acc[b].z;
          part[wave][wl][b * 4 + 3] = acc[b].w;
        }
      }
    }
    __syncthreads();

    // ---- finalize (waves 0-3): reduce + tanh + publish to IC ----
    if (tid < 256) {
      if (doC) {
        float v = isL1 ? bs : xv;
#pragma unroll
        for (int w = 0; w < 8; ++w) v += part[w][fo >> 2][fbb * 4 + (fo & 3)];
        float h = tanhf(v);
        float* hst;
        if (!isL1)
          hst = h0g + ((size_t)(s & 1) * BPG + fbb) * HH + fog;
        else {
          hst = h1g + ((size_t)((s - 1) & 1) * BPG + fbb) * HH + fog;
          pacc += h;
        }
        asm volatile("global_store_dword %0, %1, off sc0 sc1"
                     :: "v"(hst), "v"(h) : "memory");
      }
      asm volatile("s_waitcnt vmcnt(0)" ::: "memory");  // h durable at IC
      if (wl == 0) {                                    // per-wave subflag
        unsigned tp1 = (unsigned)(s + 1);
        unsigned* sf = flg + ((role << 2) + wave) * 32;
        asm volatile("global_store_dword %0, %1, off sc0 sc1"
                     :: "v"(sf), "v"(tp1) : "memory");
      }
    }

    // ---- group barrier: poll all 64 subflags (16 blocks x 4 waves) ----
    if (tid < 64) {
      const unsigned tp1 = (unsigned)(s + 1);
      unsigned* fp = flg + tid * 32;
      unsigned v;
      do {
        asm volatile("global_load_dword %0, %1, off sc0 sc1\n\t"
                     "s_waitcnt vmcnt(0)"
                     : "=v"(v) : "v"(fp) : "memory");
      } while (v < tp1);
    }
    __syncthreads();
  }

  // ---- L1 epilogue: h1_511 (uses h0_511 slot 1, h1_510 slot 0) ----
  if (isL1) {
    float4 acc[BPG] = {{0,0,0,0},{0,0,0,0},{0,0,0,0},{0,0,0,0}};
    float4 hr[4][4];
    ld_h16(hr, h0g + (size_t)1 * (BPG * HH) + jg * 16);
    asm volatile("s_waitcnt vmcnt(0)" ::: "memory");
    __builtin_amdgcn_sched_barrier(0);
    fma_mv(acc, wregA, hr);
    ld_h16(hr, h1g + jg * 16);
    asm volatile("s_waitcnt vmcnt(0)" ::: "memory");
    __builtin_amdgcn_sched_barrier(0);
    fma_mv(acc, wregB, hr);
#pragma unroll
    for (int b = 0; b < BPG; ++b) {
      acc[b].x += __shfl_down(acc[b].x, 32); acc[b].y += __shfl_down(acc[b].y, 32);
      acc[b].z += __shfl_down(acc[b].z, 32); acc[b].w += __shfl_down(acc[b].w, 32);
      acc[b].x += __shfl_down(acc[b].x, 16); acc[b].y += __shfl_down(acc[b].y, 16);
      acc[b].z += __shfl_down(acc[b].z, 16); acc[b].w += __shfl_down(acc[b].w, 16);
    }
    if (wl < 16) {
#pragma unroll
      for (int b = 0; b < BPG; ++b) {
        part[wave][wl][b * 4 + 0] = acc[b].x;
        part[wave][wl][b * 4 + 1] = acc[b].y;
        part[wave][wl][b * 4 + 2] = acc[b].z;
        part[wave][wl][b * 4 + 3] = acc[b].w;
      }
    }
    __syncthreads();
    if (tid < 256) {
      float v = bs;
#pragma unroll
      for (int w = 0; w < 8; ++w) v += part[w][fo >> 2][fbb * 4 + (fo & 3)];
      pacc += tanhf(v);
      pooled[(size_t)(grp * BPG + fbb) * HH + fog] = pacc * (1.0f / SS);
    }
  }
}

// Final head: out[b][c] = sum_k pooled[b][k] * W_out[c][k] + b_out[c]
__global__ void out_kernel(const float* __restrict__ pooled,
                           const float* __restrict__ W_out,
                           const float* __restrict__ b_out,
                           float* __restrict__ out) {
  int tid = threadIdx.x;
  if (tid >= BB * 2) return;
  int b = tid >> 1, c = tid & 1;
  float acc = b_out[c];
  for (int k = 0; k < HH; ++k)
    acc += pooled[(size_t)b * HH + k] * W_out[(size_t)c * HH + k];
  out[(size_t)b * 2 + c] = acc;
}

extern "C" void kernel_launch(void* const* d_in, const int* in_sizes, int n_in,
                              void* d_out, int out_size, void* d_ws, size_t ws_size,
                              hipStream_t stream) {
  const int*   x     = (const int*)d_in[0];
  const float* emb   = (const float*)d_in[1];
  const float* W_ih0 = (const float*)d_in[2];
  const float* W_hh0 = (const float*)d_in[3];
  const float* b_ih0 = (const float*)d_in[4];
  const float* b_hh0 = (const float*)d_in[5];
  const float* W_ih1 = (const float*)d_in[6];
  const float* W_hh1 = (const float*)d_in[7];
  const float* b_ih1 = (const float*)d_in[8];
  const float* b_hh1 = (const float*)d_in[9];
  const float* W_out = (const float*)d_in[10];
  const float* b_out = (const float*)d_in[11];

  float* ws = (float*)d_ws;
  const size_t NBSH = (size_t)BB * SS * HH;            // 16777216
  const size_t HB   = (size_t)NGROUPS * 2 * BPG * HH;  // 65536 floats
  const size_t FL   = (size_t)NGROUPS * LBLK * 4 * 32; // 131072 u32
  float* xp      = ws;                    // 64 MB
  float* WThh0   = ws + NBSH;             // 1 MB
  float* WTih1   = WThh0 + HH * HH;       // 1 MB
  float* WThh1   = WTih1 + HH * HH;       // 1 MB
  float* pooled  = WThh1 + HH * HH;       // 128 KB
  float* h0buf   = pooled + BB * HH;      // 256 KB
  float* h1buf   = h0buf + HB;            // 256 KB
  unsigned* flags = (unsigned*)(h1buf + HB);  // 512 KB

  init_sync<<<512, 256, 0, stream>>>(h0buf, h1buf, flags);

  dim3 tb(32, 8), tg(16, 16);
  transpose512<<<tg, tb, 0, stream>>>(W_hh0, WThh0);
  transpose512<<<tg, tb, 0, stream>>>(W_ih1, WTih1);
  transpose512<<<tg, tb, 0, stream>>>(W_hh1, WThh1);

  dim3 gg(512, 8);
  xp_gemm<EE, true><<<gg, 256, 0, stream>>>(nullptr, x, emb, W_ih0, b_ih0, b_hh0, xp);
  rec_fused<<<NGROUPS * LBLK, RECT, 0, stream>>>(
      xp, WThh0, WTih1, WThh1, b_ih1, b_hh1, pooled, h0buf, h1buf, flags);
  out_kernel<<<1, 128, 0, stream>>>(pooled, W_out, b_out, (float*)d_out);
}

// Round 11
// 2034.353 us; speedup vs baseline: 3.4876x; 1.0551x over previous
//
#include <hip/hip_runtime.h>
#include <math.h>

// Problem constants
#define BB 64      // batch
#define SS 512     // seq
#define EE 256     // embed
#define HH 512     // hidden

// Round-11: fused two-layer pipelined recurrence with LDS-staged h.
// Round-10 profile showed ~49MB/step of redundant IC reads (16 threads per
// jg pulled identical 64B, sc0sc1 bypasses all broadcast-capable caches) =
// ~12TB/s at the IC = the bottleneck. Now each block does ONE cooperative
// 8KB (L0) / 16KB (L1, both slots together) IC read per step into LDS, and
// the FMA loop reads h from LDS (same-addr across 16 lanes = free
// broadcast). IC read traffic drops 32x; L1's two matvec phases run
// back-to-back with a single stage wait.
// Sync protocol unchanged from round 9/10: IC-direct sc0sc1 h publish ->
// per-wave vmcnt -> subflag -> lanes poll 64 subflags -> syncthreads.
#define NGROUPS 16
#define GSLICES 8          // slices per layer per group
#define LBLK 16            // blocks per group (2 layers x 8 slices)
#define BPG 4              // batches per group
#define RECT 512           // threads per rec block

// ---------------------------------------------------------------------------

// W transpose: WT[j][i] = W[i][j], 512x512
__global__ void transpose512(const float* __restrict__ in, float* __restrict__ out) {
  __shared__ float tile[32][33];
  int bx = blockIdx.x * 32, by = blockIdx.y * 32;
  int x = threadIdx.x, y0 = threadIdx.y;  // block (32,8)
  for (int dy = 0; dy < 32; dy += 8)
    tile[y0 + dy][x] = in[(size_t)(by + y0 + dy) * HH + bx + x];
  __syncthreads();
  for (int dy = 0; dy < 32; dy += 8)
    out[(size_t)(bx + y0 + dy) * HH + by + x] = tile[x][y0 + dy];
}

// Tiled GEMM with gather: C[m][n] = sum_k emb[x[m]][k] * Wn[n][k] + b1[n]+b2[n]
template <int K, bool GATHER>
__global__ __launch_bounds__(256) void xp_gemm(
    const float* __restrict__ Asrc, const int* __restrict__ xidx,
    const float* __restrict__ emb, const float* __restrict__ Wn,
    const float* __restrict__ bias1, const float* __restrict__ bias2,
    float* __restrict__ C) {
  const int tid = threadIdx.x;
  const int m0 = blockIdx.x * 64;
  const int n0 = blockIdx.y * 64;
  __shared__ alignas(16) float As[32][68];
  __shared__ alignas(16) float Bs[32][68];
  __shared__ int xs[64];
  if (GATHER) {
    if (tid < 64) xs[tid] = xidx[m0 + tid];
    __syncthreads();
  }
  float acc[4][4] = {};
  const int ty = tid >> 4, tx = tid & 15;
  const int row = tid >> 2;          // 0..63
  const int kc = (tid & 3) * 8;      // 0,8,16,24

  for (int k0 = 0; k0 < K; k0 += 32) {
    const float* ap;
    if (GATHER) ap = emb + (size_t)xs[row] * EE + (k0 + kc);
    else        ap = Asrc + (size_t)(m0 + row) * K + (k0 + kc);
    float4 av0 = *(const float4*)ap;
    float4 av1 = *(const float4*)(ap + 4);
    const float* bp = Wn + (size_t)(n0 + row) * K + (k0 + kc);
    float4 bv0 = *(const float4*)bp;
    float4 bv1 = *(const float4*)(bp + 4);
    __syncthreads();
    As[kc + 0][row] = av0.x; As[kc + 1][row] = av0.y;
    As[kc + 2][row] = av0.z; As[kc + 3][row] = av0.w;
    As[kc + 4][row] = av1.x; As[kc + 5][row] = av1.y;
    As[kc + 6][row] = av1.z; As[kc + 7][row] = av1.w;
    Bs[kc + 0][row] = bv0.x; Bs[kc + 1][row] = bv0.y;
    Bs[kc + 2][row] = bv0.z; Bs[kc + 3][row] = bv0.w;
    Bs[kc + 4][row] = bv1.x; Bs[kc + 5][row] = bv1.y;
    Bs[kc + 6][row] = bv1.z; Bs[kc + 7][row] = bv1.w;
    __syncthreads();
#pragma unroll 8
    for (int k = 0; k < 32; ++k) {
      float4 av = *(const float4*)&As[k][ty * 4];
      float4 bv = *(const float4*)&Bs[k][tx * 4];
      acc[0][0] += av.x * bv.x; acc[0][1] += av.x * bv.y;
      acc[0][2] += av.x * bv.z; acc[0][3] += av.x * bv.w;
      acc[1][0] += av.y * bv.x; acc[1][1] += av.y * bv.y;
      acc[1][2] += av.y * bv.z; acc[1][3] += av.y * bv.w;
      acc[2][0] += av.z * bv.x; acc[2][1] += av.z * bv.y;
      acc[2][2] += av.z * bv.z; acc[2][3] += av.z * bv.w;
      acc[3][0] += av.w * bv.x; acc[3][1] += av.w * bv.y;
      acc[3][2] += av.w * bv.z; acc[3][3] += av.w * bv.w;
    }
  }
  float bj[4];
#pragma unroll
  for (int j = 0; j < 4; ++j) {
    int n = n0 + tx * 4 + j;
    bj[j] = bias1[n] + bias2[n];
  }
#pragma unroll
  for (int i = 0; i < 4; ++i) {
    float4 cv = make_float4(acc[i][0] + bj[0], acc[i][1] + bj[1],
                            acc[i][2] + bj[2], acc[i][3] + bj[3]);
    *(float4*)&C[(size_t)(m0 + ty * 4 + i) * HH + n0 + tx * 4] = cv;
  }
}

// Initialize h-exchange buffers + flags AT THE IC (system-scope stores emit
// sc0 sc1 -- rec only touches these lines cache-bypassed). Every launch.
__global__ void init_sync(float* __restrict__ h0b, float* __restrict__ h1b,
                          unsigned* __restrict__ flags) {
  int i = blockIdx.x * 256 + threadIdx.x;
  if (i < NGROUPS * 2 * BPG * HH) {
    __hip_atomic_store(&h0b[i], 0.f, __ATOMIC_RELAXED, __HIP_MEMORY_SCOPE_SYSTEM);
    __hip_atomic_store(&h1b[i], 0.f, __ATOMIC_RELAXED, __HIP_MEMORY_SCOPE_SYSTEM);
  }
  if (i < NGROUPS * LBLK * 4 * 32)
    __hip_atomic_store(&flags[i], 0u, __ATOMIC_RELAXED, __HIP_MEMORY_SCOPE_SYSTEM);
}

__device__ __forceinline__ void fma4(float4& d, const float4 w, const float s) {
  d.x = __builtin_fmaf(w.x, s, d.x);
  d.y = __builtin_fmaf(w.y, s, d.y);
  d.z = __builtin_fmaf(w.z, s, d.z);
  d.w = __builtin_fmaf(w.w, s, d.w);
}

__device__ __forceinline__ float4 ic_ld4(const float* p) {
  float4 v;
  asm volatile("global_load_dwordx4 %0, %1, off sc0 sc1" : "=v"(v) : "v"(p));
  return v;
}

// matvec phase from LDS-staged h: acc[b] += sum_j wreg[j] * h[b][jg*16+j]
// (inlined -> compiler sees the LDS address space; 16 lanes sharing jg read
//  the same address = free broadcast)
__device__ __forceinline__ void fma_mv_lds(float4 acc[4], const float4 wreg[16],
                                           const float* h, int jg) {
#pragma unroll
  for (int q = 0; q < 4; ++q) {
    float4 w0 = wreg[q * 4 + 0], w1 = wreg[q * 4 + 1];
    float4 w2 = wreg[q * 4 + 2], w3 = wreg[q * 4 + 3];
#pragma unroll
    for (int b = 0; b < 4; ++b) {
      float4 hv = *(const float4*)&h[b * HH + jg * 16 + q * 4];
      fma4(acc[b], w0, hv.x);
      fma4(acc[b], w1, hv.y);
      fma4(acc[b], w2, hv.z);
      fma4(acc[b], w3, hv.w);
    }
  }
}

// 16x dwordx4 sc0sc1 direct loads (epilogue only). 13-bit signed imm offset.
__device__ __forceinline__ void ld_h16(float4 hr[4][4], const float* hp0) {
  const float* hp2 = hp0 + 2 * HH;   // +4096 bytes
  asm volatile(
    "global_load_dwordx4 %0, %4, off sc0 sc1\n\t"
    "global_load_dwordx4 %1, %4, off offset:16 sc0 sc1\n\t"
    "global_load_dwordx4 %2, %4, off offset:32 sc0 sc1\n\t"
    "global_load_dwordx4 %3, %4, off offset:48 sc0 sc1"
    : "=&v"(hr[0][0]), "=&v"(hr[0][1]), "=&v"(hr[0][2]), "=&v"(hr[0][3])
    : "v"(hp0));
  asm volatile(
    "global_load_dwordx4 %0, %4, off offset:2048 sc0 sc1\n\t"
    "global_load_dwordx4 %1, %4, off offset:2064 sc0 sc1\n\t"
    "global_load_dwordx4 %2, %4, off offset:2080 sc0 sc1\n\t"
    "global_load_dwordx4 %3, %4, off offset:2096 sc0 sc1"
    : "=&v"(hr[1][0]), "=&v"(hr[1][1]), "=&v"(hr[1][2]), "=&v"(hr[1][3])
    : "v"(hp0));
  asm volatile(
    "global_load_dwordx4 %0, %4, off sc0 sc1\n\t"
    "global_load_dwordx4 %1, %4, off offset:16 sc0 sc1\n\t"
    "global_load_dwordx4 %2, %4, off offset:32 sc0 sc1\n\t"
    "global_load_dwordx4 %3, %4, off offset:48 sc0 sc1"
    : "=&v"(hr[2][0]), "=&v"(hr[2][1]), "=&v"(hr[2][2]), "=&v"(hr[2][3])
    : "v"(hp2));
  asm volatile(
    "global_load_dwordx4 %0, %4, off offset:2048 sc0 sc1\n\t"
    "global_load_dwordx4 %1, %4, off offset:2064 sc0 sc1\n\t"
    "global_load_dwordx4 %2, %4, off offset:2080 sc0 sc1\n\t"
    "global_load_dwordx4 %3, %4, off offset:2096 sc0 sc1"
    : "=&v"(hr[3][0]), "=&v"(hr[3][1]), "=&v"(hr[3][2]), "=&v"(hr[3][3])
    : "v"(hp2));
}

__device__ __forceinline__ void fma_mv(float4 acc[4], const float4 wreg[16],
                                       const float4 hr[4][4]) {
#pragma unroll
  for (int q = 0; q < 4; ++q) {
    float4 w0 = wreg[q * 4 + 0], w1 = wreg[q * 4 + 1];
    float4 w2 = wreg[q * 4 + 2], w3 = wreg[q * 4 + 3];
#pragma unroll
    for (int b = 0; b < 4; ++b) {
      float4 hv = hr[b][q];
      fma4(acc[b], w0, hv.x);
      fma4(acc[b], w1, hv.y);
      fma4(acc[b], w2, hv.z);
      fma4(acc[b], w3, hv.w);
    }
  }
}

// Fused 2-layer recurrence. bid: grp = bid&15, role = bid>>4 (0..7 = L0
// slices, 8..15 = L1 slices). Thread (oo4=tid&15, jg=tid>>4): outputs
// obase..obase+3, j-range [jg*16,+16), 4 batches.
__global__ __launch_bounds__(RECT, 2) void rec_fused(
    const float* __restrict__ xp,      // [BB][SS][HH] (layer-0 input proj)
    const float* __restrict__ WThh0,   // [HH][HH]
    const float* __restrict__ WTih1,   // [HH][HH]
    const float* __restrict__ WThh1,   // [HH][HH]
    const float* __restrict__ b_ih1,
    const float* __restrict__ b_hh1,
    float* __restrict__ pooled,        // [BB][HH]
    float* __restrict__ h0b,           // [NGROUPS][2][BPG][HH] (IC lines)
    float* __restrict__ h1b,           // [NGROUPS][2][BPG][HH]
    unsigned* __restrict__ flags) {    // [NGROUPS][LBLK*4][32]
  const int tid = threadIdx.x;
  const int bid = blockIdx.x;
  const int grp = bid & 15;
  const int role = bid >> 4;          // 0..15
  const bool isL1 = role >= GSLICES;
  const int slice = role & 7;
  const int oo4 = tid & 15;
  const int jg = tid >> 4;            // 0..31
  const int obase = slice * 64 + oo4 * 4;

  // ---- weights into registers (once); pin against remat (round-4 lesson) --
  float4 wregA[16], wregB[16];
  {
    const float* wb = isL1 ? WThh1 : WThh0;
#pragma unroll
    for (int j = 0; j < 16; ++j)
      wregB[j] = *(const float4*)&wb[(size_t)(jg * 16 + j) * HH + obase];
#pragma unroll
    for (int j = 0; j < 16; ++j)
      asm volatile("" : "+v"(wregB[j].x), "+v"(wregB[j].y),
                        "+v"(wregB[j].z), "+v"(wregB[j].w));
  }
  if (isL1) {
#pragma unroll
    for (int j = 0; j < 16; ++j)
      wregA[j] = *(const float4*)&WTih1[(size_t)(jg * 16 + j) * HH + obase];
#pragma unroll
    for (int j = 0; j < 16; ++j)
      asm volatile("" : "+v"(wregA[j].x), "+v"(wregA[j].y),
                        "+v"(wregA[j].z), "+v"(wregA[j].w));
  }

  float* h0g = h0b + (size_t)grp * (2 * BPG * HH);
  float* h1g = h1b + (size_t)grp * (2 * BPG * HH);
  unsigned* flg = flags + (size_t)grp * (LBLK * 4 * 32);

  __shared__ alignas(16) float hA[BPG * HH];   // 8 KB staged slot
  __shared__ alignas(16) float hB[BPG * HH];   // 8 KB (L1 only)
  __shared__ float part[8][16][17];            // [wave][oo4][b*4+c], padded

  const int wave = tid >> 6, wl = tid & 63;
  const int fo = tid & 63;                 // finalize: output within slice
  const int fbb = (tid >> 6) & 3;          // finalize: batch (tid<256)
  const int fog = slice * 64 + fo;
  const size_t fxbase = (size_t)(grp * BPG + fbb) * (SS * HH) + fog;
  float pacc = 0.f;
  float bs = 0.f;
  if (tid < 256) bs = b_ih1[fog] + b_hh1[fog];   // L1 bias sum (L0: unused)

  for (int s = 0; s < SS; ++s) {
    const bool doC = (!isL1) || (s >= 1);
    float4 acc[BPG] = {{0,0,0,0},{0,0,0,0},{0,0,0,0},{0,0,0,0}};
    float xv = 0.f;
    if (doC) {
      // ---- cooperative stage: one 8/16KB IC read into LDS ----
      const float* srcA;
      const float* srcB = nullptr;
      if (!isL1) {
        srcA = h0g + (size_t)((s + 1) & 1) * (BPG * HH);
      } else {
        srcA = h0g + (size_t)((s - 1) & 1) * (BPG * HH);  // h0_{s-1}
        srcB = h1g + (size_t)(s & 1) * (BPG * HH);        // h1_{s-2}
      }
      float4 va = ic_ld4(srcA + tid * 4);
      float4 vb;
      if (isL1) vb = ic_ld4(srcB + tid * 4);
      if (!isL1 && tid < 256) xv = xp[fxbase + (size_t)s * HH];  // cached
      asm volatile("s_waitcnt vmcnt(0)" ::: "memory");
      __builtin_amdgcn_sched_barrier(0);
      *(float4*)&hA[tid * 4] = va;
      if (isL1) *(float4*)&hB[tid * 4] = vb;
      __syncthreads();   // stage visible

      // ---- matvec(s) from LDS (broadcast reads) ----
      if (!isL1) {
        fma_mv_lds(acc, wregB, hA, jg);
      } else {
        fma_mv_lds(acc, wregA, hA, jg);   // W_ih1 * h0_{s-1}
        fma_mv_lds(acc, wregB, hB, jg);   // + W_hh1 * h1_{s-2}
      }

      // ---- reduce over jg: 4 j-groups within wave via shfl ----
#pragma unroll
      for (int b = 0; b < BPG; ++b) {
        acc[b].x += __shfl_down(acc[b].x, 32); acc[b].y += __shfl_down(acc[b].y, 32);
        acc[b].z += __shfl_down(acc[b].z, 32); acc[b].w += __shfl_down(acc[b].w, 32);
        acc[b].x += __shfl_down(acc[b].x, 16); acc[b].y += __shfl_down(acc[b].y, 16);
        acc[b].z += __shfl_down(acc[b].z, 16); acc[b].w += __shfl_down(acc[b].w, 16);
      }
      if (wl < 16) {
#pragma unroll
        for (int b = 0; b < BPG; ++b) {
          part[wave][wl][b * 4 + 0] = acc[b].x;
          part[wave][wl][b * 4 + 1] = acc[b].y;
          part[wave][wl][b * 4 + 2] = acc[b].z;
          part[wave][wl][b * 4 + 3] = acc[b].w;
        }
      }
    }
    __syncthreads();

    // ---- finalize (waves 0-3): reduce + tanh + publish to IC ----
    if (tid < 256) {
      if (doC) {
        float v = isL1 ? bs : xv;
#pragma unroll
        for (int w = 0; w < 8; ++w) v += part[w][fo >> 2][fbb * 4 + (fo & 3)];
        float h = tanhf(v);
        float* hst;
        if (!isL1)
          hst = h0g + ((size_t)(s & 1) * BPG + fbb) * HH + fog;
        else {
          hst = h1g + ((size_t)((s - 1) & 1) * BPG + fbb) * HH + fog;
          pacc += h;
        }
        asm volatile("global_store_dword %0, %1, off sc0 sc1"
                     :: "v"(hst), "v"(h) : "memory");
      }
      asm volatile("s_waitcnt vmcnt(0)" ::: "memory");  // h durable at IC
      if (wl == 0) {                                    // per-wave subflag
        unsigned tp1 = (unsigned)(s + 1);
        unsigned* sf = flg + ((role << 2) + wave) * 32;
        asm volatile("global_store_dword %0, %1, off sc0 sc1"
                     :: "v"(sf), "v"(tp1) : "memory");
      }
    }

    // ---- group barrier: poll all 64 subflags (16 blocks x 4 waves) ----
    if (tid < 64) {
      const unsigned tp1 = (unsigned)(s + 1);
      unsigned* fp = flg + tid * 32;
      unsigned v;
      do {
        asm volatile("global_load_dword %0, %1, off sc0 sc1\n\t"
                     "s_waitcnt vmcnt(0)"
                     : "=v"(v) : "v"(fp) : "memory");
      } while (v < tp1);
    }
    __syncthreads();
  }

  // ---- L1 epilogue: h1_511 (uses h0_511 slot 1, h1_510 slot 0) ----
  if (isL1) {
    float4 acc[BPG] = {{0,0,0,0},{0,0,0,0},{0,0,0,0},{0,0,0,0}};
    float4 hr[4][4];
    ld_h16(hr, h0g + (size_t)1 * (BPG * HH) + jg * 16);
    asm volatile("s_waitcnt vmcnt(0)" ::: "memory");
    __builtin_amdgcn_sched_barrier(0);
    fma_mv(acc, wregA, hr);
    ld_h16(hr, h1g + jg * 16);
    asm volatile("s_waitcnt vmcnt(0)" ::: "memory");
    __builtin_amdgcn_sched_barrier(0);
    fma_mv(acc, wregB, hr);
#pragma unroll
    for (int b = 0; b < BPG; ++b) {
      acc[b].x += __shfl_down(acc[b].x, 32); acc[b].y += __shfl_down(acc[b].y, 32);
      acc[b].z += __shfl_down(acc[b].z, 32); acc[b].w += __shfl_down(acc[b].w, 32);
      acc[b].x += __shfl_down(acc[b].x, 16); acc[b].y += __shfl_down(acc[b].y, 16);
      acc[b].z += __shfl_down(acc[b].z, 16); acc[b].w += __shfl_down(acc[b].w, 16);
    }
    if (wl < 16) {
#pragma unroll
      for (int b = 0; b < BPG; ++b) {
        part[wave][wl][b * 4 + 0] = acc[b].x;
        part[wave][wl][b * 4 + 1] = acc[b].y;
        part[wave][wl][b * 4 + 2] = acc[b].z;
        part[wave][wl][b * 4 + 3] = acc[b].w;
      }
    }
    __syncthreads();
    if (tid < 256) {
      float v = bs;
#pragma unroll
      for (int w = 0; w < 8; ++w) v += part[w][fo >> 2][fbb * 4 + (fo & 3)];
      pacc += tanhf(v);
      pooled[(size_t)(grp * BPG + fbb) * HH + fog] = pacc * (1.0f / SS);
    }
  }
}

// Final head: out[b][c] = sum_k pooled[b][k] * W_out[c][k] + b_out[c]
__global__ void out_kernel(const float* __restrict__ pooled,
                           const float* __restrict__ W_out,
                           const float* __restrict__ b_out,
                           float* __restrict__ out) {
  int tid = threadIdx.x;
  if (tid >= BB * 2) return;
  int b = tid >> 1, c = tid & 1;
  float acc = b_out[c];
  for (int k = 0; k < HH; ++k)
    acc += pooled[(size_t)b * HH + k] * W_out[(size_t)c * HH + k];
  out[(size_t)b * 2 + c] = acc;
}

extern "C" void kernel_launch(void* const* d_in, const int* in_sizes, int n_in,
                              void* d_out, int out_size, void* d_ws, size_t ws_size,
                              hipStream_t stream) {
  const int*   x     = (const int*)d_in[0];
  const float* emb   = (const float*)d_in[1];
  const float* W_ih0 = (const float*)d_in[2];
  const float* W_hh0 = (const float*)d_in[3];
  const float* b_ih0 = (const float*)d_in[4];
  const float* b_hh0 = (const float*)d_in[5];
  const float* W_ih1 = (const float*)d_in[6];
  const float* W_hh1 = (const float*)d_in[7];
  const float* b_ih1 = (const float*)d_in[8];
  const float* b_hh1 = (const float*)d_in[9];
  const float* W_out = (const float*)d_in[10];
  const float* b_out = (const float*)d_in[11];

  float* ws = (float*)d_ws;
  const size_t NBSH = (size_t)BB * SS * HH;            // 16777216
  const size_t HB   = (size_t)NGROUPS * 2 * BPG * HH;  // 65536 floats
  const size_t FL   = (size_t)NGROUPS * LBLK * 4 * 32; // 32768 u32
  float* xp      = ws;                    // 64 MB
  float* WThh0   = ws + NBSH;             // 1 MB
  float* WTih1   = WThh0 + HH * HH;       // 1 MB
  float* WThh1   = WTih1 + HH * HH;       // 1 MB
  float* pooled  = WThh1 + HH * HH;       // 128 KB
  float* h0buf   = pooled + BB * HH;      // 256 KB
  float* h1buf   = h0buf + HB;            // 256 KB
  unsigned* flags = (unsigned*)(h1buf + HB);  // 128 KB

  init_sync<<<512, 256, 0, stream>>>(h0buf, h1buf, flags);

  dim3 tb(32, 8), tg(16, 16);
  transpose512<<<tg, tb, 0, stream>>>(W_hh0, WThh0);
  transpose512<<<tg, tb, 0, stream>>>(W_ih1, WTih1);
  transpose512<<<tg, tb, 0, stream>>>(W_hh1, WThh1);

  dim3 gg(512, 8);
  xp_gemm<EE, true><<<gg, 256, 0, stream>>>(nullptr, x, emb, W_ih0, b_ih0, b_hh0, xp);
  rec_fused<<<NGROUPS * LBLK, RECT, 0, stream>>>(
      xp, WThh0, WTih1, WThh1, b_ih1, b_hh1, pooled, h0buf, h1buf, flags);
  out_kernel<<<1, 128, 0, stream>>>(pooled, W_out, b_out, (float*)d_out);
}

// Round 13
// 2034.259 us; speedup vs baseline: 3.4878x; 1.0000x over previous
//
#include <hip/hip_runtime.h>
#include <math.h>

// Problem constants
#define BB 64      // batch
#define SS 512     // seq
#define EE 256     // embed
#define HH 512     // hidden

// Round-13: fused 2-layer recurrence with LL-PACKET exchange (RCCL-style).
// r12's XCD-L2 fast path HUNG: plain stores are not visible to peer sc0
// loads (no architectural XCD-local exchange scope) -- reverted.
// Instead, attack r11's serialized inter-block chain (h-store -> vmcnt ack
// -> flag store -> flag poll -> separate h load ~= 2.4Kcyc/step) with
// 8-byte {data,tag} packets stored by one global_store_dwordx2 sc0 sc1
// (8B single-copy atomic at the IC -- the RCCL LL protocol granule):
// the store IS the release (no ack wait), and the consumer's poll load IS
// the stage (tag==step => payload in the same 8B is valid).
// Ring of 16 slots/layer; full flag-barrier every 8 steps bounds skew <8
// so tags never lap. s_sleep(1) backoff bounds poll traffic.
#define NGROUPS 16
#define GSLICES 8          // slices per layer per group
#define LBLK 16            // blocks per group (2 layers x 8 slices)
#define BPG 4              // batches per group
#define RECT 512           // threads per rec block
#define RING 16            // ring slots per layer
#define BARK 8             // full barrier every BARK steps

#define SLOTF (GSLICES * 512)        // floats per (layer,slot): 2048 pkts x 2
#define GPKF  (2 * RING * SLOTF)     // floats per group packet region

// ---------------------------------------------------------------------------

// W transpose: WT[j][i] = W[i][j], 512x512
__global__ void transpose512(const float* __restrict__ in, float* __restrict__ out) {
  __shared__ float tile[32][33];
  int bx = blockIdx.x * 32, by = blockIdx.y * 32;
  int x = threadIdx.x, y0 = threadIdx.y;  // block (32,8)
  for (int dy = 0; dy < 32; dy += 8)
    tile[y0 + dy][x] = in[(size_t)(by + y0 + dy) * HH + bx + x];
  __syncthreads();
  for (int dy = 0; dy < 32; dy += 8)
    out[(size_t)(bx + y0 + dy) * HH + by + x] = tile[x][y0 + dy];
}

// Tiled GEMM with gather: C[m][n] = sum_k emb[x[m]][k] * Wn[n][k] + b1[n]+b2[n]
template <int K, bool GATHER>
__global__ __launch_bounds__(256) void xp_gemm(
    const float* __restrict__ Asrc, const int* __restrict__ xidx,
    const float* __restrict__ emb, const float* __restrict__ Wn,
    const float* __restrict__ bias1, const float* __restrict__ bias2,
    float* __restrict__ C) {
  const int tid = threadIdx.x;
  const int m0 = blockIdx.x * 64;
  const int n0 = blockIdx.y * 64;
  __shared__ alignas(16) float As[32][68];
  __shared__ alignas(16) float Bs[32][68];
  __shared__ int xs[64];
  if (GATHER) {
    if (tid < 64) xs[tid] = xidx[m0 + tid];
    __syncthreads();
  }
  float acc[4][4] = {};
  const int ty = tid >> 4, tx = tid & 15;
  const int row = tid >> 2;          // 0..63
  const int kc = (tid & 3) * 8;      // 0,8,16,24

  for (int k0 = 0; k0 < K; k0 += 32) {
    const float* ap;
    if (GATHER) ap = emb + (size_t)xs[row] * EE + (k0 + kc);
    else        ap = Asrc + (size_t)(m0 + row) * K + (k0 + kc);
    float4 av0 = *(const float4*)ap;
    float4 av1 = *(const float4*)(ap + 4);
    const float* bp = Wn + (size_t)(n0 + row) * K + (k0 + kc);
    float4 bv0 = *(const float4*)bp;
    float4 bv1 = *(const float4*)(bp + 4);
    __syncthreads();
    As[kc + 0][row] = av0.x; As[kc + 1][row] = av0.y;
    As[kc + 2][row] = av0.z; As[kc + 3][row] = av0.w;
    As[kc + 4][row] = av1.x; As[kc + 5][row] = av1.y;
    As[kc + 6][row] = av1.z; As[kc + 7][row] = av1.w;
    Bs[kc + 0][row] = bv0.x; Bs[kc + 1][row] = bv0.y;
    Bs[kc + 2][row] = bv0.z; Bs[kc + 3][row] = bv0.w;
    Bs[kc + 4][row] = bv1.x; Bs[kc + 5][row] = bv1.y;
    Bs[kc + 6][row] = bv1.z; Bs[kc + 7][row] = bv1.w;
    __syncthreads();
#pragma unroll 8
    for (int k = 0; k < 32; ++k) {
      float4 av = *(const float4*)&As[k][ty * 4];
      float4 bv = *(const float4*)&Bs[k][tx * 4];
      acc[0][0] += av.x * bv.x; acc[0][1] += av.x * bv.y;
      acc[0][2] += av.x * bv.z; acc[0][3] += av.x * bv.w;
      acc[1][0] += av.y * bv.x; acc[1][1] += av.y * bv.y;
      acc[1][2] += av.y * bv.z; acc[1][3] += av.y * bv.w;
      acc[2][0] += av.z * bv.x; acc[2][1] += av.z * bv.y;
      acc[2][2] += av.z * bv.z; acc[2][3] += av.z * bv.w;
      acc[3][0] += av.w * bv.x; acc[3][1] += av.w * bv.y;
      acc[3][2] += av.w * bv.z; acc[3][3] += av.w * bv.w;
    }
  }
  float bj[4];
#pragma unroll
  for (int j = 0; j < 4; ++j) {
    int n = n0 + tx * 4 + j;
    bj[j] = bias1[n] + bias2[n];
  }
#pragma unroll
  for (int i = 0; i < 4; ++i) {
    float4 cv = make_float4(acc[i][0] + bj[0], acc[i][1] + bj[1],
                            acc[i][2] + bj[2], acc[i][3] + bj[3]);
    *(float4*)&C[(size_t)(m0 + ty * 4 + i) * HH + n0 + tx * 4] = cv;
  }
}

// Zero packet region + barrier flags AT THE IC (system-scope stores emit
// sc0 sc1; packets are only ever accessed cache-bypassed, so the IC copy
// must be the home). Runs every launch (graph replays don't re-poison;
// stale tags from a previous launch must not alias fresh ones).
__global__ void init_sync(float* __restrict__ pkts, unsigned* __restrict__ flags) {
  size_t i = (size_t)blockIdx.x * 256 + threadIdx.x;
  if (i < (size_t)NGROUPS * GPKF)
    __hip_atomic_store(&pkts[i], 0.f, __ATOMIC_RELAXED, __HIP_MEMORY_SCOPE_SYSTEM);
  if (i < NGROUPS * LBLK * 32)
    __hip_atomic_store(&flags[i], 0u, __ATOMIC_RELAXED, __HIP_MEMORY_SCOPE_SYSTEM);
}

__device__ __forceinline__ void fma4(float4& d, const float4 w, const float s) {
  d.x = __builtin_fmaf(w.x, s, d.x);
  d.y = __builtin_fmaf(w.y, s, d.y);
  d.z = __builtin_fmaf(w.z, s, d.z);
  d.w = __builtin_fmaf(w.w, s, d.w);
}

// Poll 4 packets (32B) at pb + tid*32: loads and tag checks fused.
__device__ __forceinline__ void poll2(const float* pb, unsigned tg,
                                      float4& u0, float4& u1) {
  for (;;) {
    asm volatile(
      "global_load_dwordx4 %0, %2, off sc0 sc1\n\t"
      "global_load_dwordx4 %1, %2, off offset:16 sc0 sc1\n\t"
      "s_waitcnt vmcnt(0)"
      : "=&v"(u0), "=&v"(u1) : "v"(pb) : "memory");
    if (__float_as_uint(u0.y) == tg && __float_as_uint(u0.w) == tg &&
        __float_as_uint(u1.y) == tg && __float_as_uint(u1.w) == tg) break;
    __builtin_amdgcn_s_sleep(1);
  }
}

// Poll 8 packets from two regions (h0 + h1) in one retry loop.
__device__ __forceinline__ void poll4(const float* pa, unsigned tga,
                                      const float* pb, unsigned tgb,
                                      float4& a0, float4& a1,
                                      float4& b0, float4& b1) {
  for (;;) {
    asm volatile(
      "global_load_dwordx4 %0, %4, off sc0 sc1\n\t"
      "global_load_dwordx4 %1, %4, off offset:16 sc0 sc1\n\t"
      "global_load_dwordx4 %2, %5, off sc0 sc1\n\t"
      "global_load_dwordx4 %3, %5, off offset:16 sc0 sc1\n\t"
      "s_waitcnt vmcnt(0)"
      : "=&v"(a0), "=&v"(a1), "=&v"(b0), "=&v"(b1)
      : "v"(pa), "v"(pb) : "memory");
    if (__float_as_uint(a0.y) == tga && __float_as_uint(a0.w) == tga &&
        __float_as_uint(a1.y) == tga && __float_as_uint(a1.w) == tga &&
        __float_as_uint(b0.y) == tgb && __float_as_uint(b0.w) == tgb &&
        __float_as_uint(b1.y) == tgb && __float_as_uint(b1.w) == tgb) break;
    __builtin_amdgcn_s_sleep(1);
  }
}

// Scatter 4 packet payloads into the staged LDS h array.
// Packet q: slice = q>>8, b = (q>>6)&3, oo = q&63, j = slice*64+oo.
// q0 = tid*4 -> the 4 payloads are (b, j0..j0+3) contiguous, 16B-aligned.
__device__ __forceinline__ void scat(float* hs, int q0, float4 u0, float4 u1) {
  int b = (q0 >> 6) & 3;
  int j0 = (q0 >> 8) * 64 + (q0 & 63);
  *(float4*)&hs[b * HH + j0] = make_float4(u0.x, u0.z, u1.x, u1.z);
}

// matvec from LDS-staged h (16 lanes sharing jg read same addr = broadcast)
__device__ __forceinline__ void fma_mv_lds(float4 acc[4], const float4 wreg[16],
                                           const float* h, int jg) {
#pragma unroll
  for (int q = 0; q < 4; ++q) {
    float4 w0 = wreg[q * 4 + 0], w1 = wreg[q * 4 + 1];
    float4 w2 = wreg[q * 4 + 2], w3 = wreg[q * 4 + 3];
#pragma unroll
    for (int b = 0; b < 4; ++b) {
      float4 hv = *(const float4*)&h[b * HH + jg * 16 + q * 4];
      fma4(acc[b], w0, hv.x);
      fma4(acc[b], w1, hv.y);
      fma4(acc[b], w2, hv.z);
      fma4(acc[b], w3, hv.w);
    }
  }
}

// Fused 2-layer recurrence. bid: grp = bid&15, role = bid>>4
// (0..7 = L0 slices, 8..15 = L1 slices).
// Packets: h0_s -> layer 0, slot s&15, tag s+1. h1_t -> layer 1, slot t&15,
// tag t+1 (written at step s=t+1). Consumers at step s read h0_{s-1}
// (tag s) and, for L1, h1_{s-2} (tag s-1).
__global__ __launch_bounds__(RECT, 2) void rec_fused(
    const float* __restrict__ xp,      // [BB][SS][HH]
    const float* __restrict__ WThh0,   // [HH][HH]
    const float* __restrict__ WTih1,   // [HH][HH]
    const float* __restrict__ WThh1,   // [HH][HH]
    const float* __restrict__ b_ih1,
    const float* __restrict__ b_hh1,
    float* __restrict__ pooled,        // [BB][HH]
    float* __restrict__ pkts,          // [NGROUPS][2][RING][GSLICES*256 pkts]
    unsigned* __restrict__ flags) {    // [NGROUPS][LBLK][32]
  const int tid = threadIdx.x;
  const int bid = blockIdx.x;
  const int grp = bid & 15;
  const int role = bid >> 4;          // 0..15
  const bool isL1 = role >= GSLICES;
  const int slice = role & 7;
  const int oo4 = tid & 15;
  const int jg = tid >> 4;            // 0..31
  const int obase = slice * 64 + oo4 * 4;

  // ---- weights into registers (once); pin against remat (round-4 lesson) --
  float4 wregA[16], wregB[16];
  {
    const float* wb = isL1 ? WThh1 : WThh0;
#pragma unroll
    for (int j = 0; j < 16; ++j)
      wregB[j] = *(const float4*)&wb[(size_t)(jg * 16 + j) * HH + obase];
#pragma unroll
    for (int j = 0; j < 16; ++j)
      asm volatile("" : "+v"(wregB[j].x), "+v"(wregB[j].y),
                        "+v"(wregB[j].z), "+v"(wregB[j].w));
  }
  if (isL1) {
#pragma unroll
    for (int j = 0; j < 16; ++j)
      wregA[j] = *(const float4*)&WTih1[(size_t)(jg * 16 + j) * HH + obase];
#pragma unroll
    for (int j = 0; j < 16; ++j)
      asm volatile("" : "+v"(wregA[j].x), "+v"(wregA[j].y),
                        "+v"(wregA[j].z), "+v"(wregA[j].w));
  }

  float* pk = pkts + (size_t)grp * GPKF;
  unsigned* flg = flags + grp * (LBLK * 32);

  __shared__ alignas(16) float hA[BPG * HH];   // 8 KB
  __shared__ alignas(16) float hB[BPG * HH];   // 8 KB
  __shared__ float part[8][16][17];

  const int wave = tid >> 6, wl = tid & 63;
  const int fo = tid & 63;
  const int fbb = (tid >> 6) & 3;
  const int fog = slice * 64 + fo;
  const size_t fxbase = (size_t)(grp * BPG + fbb) * (SS * HH) + fog;
  float pacc = 0.f;
  float bs = 0.f;
  if (tid < 256) bs = b_ih1[fog] + b_hh1[fog];

  const int q0 = tid * 4;            // this thread's 4 packets
  const int toff = tid * 8;          // float offset of those packets
  // writer packet float offset within a slot
  const int wpo = slice * 512 + (fbb * 64 + fo) * 2;

  for (int s = 0; s < SS; ++s) {
    float xv = 0.f;
    // ---- stage: poll packets (detect == stage) ----
    if (!isL1) {
      if (tid < 256) xv = xp[fxbase + (size_t)s * HH];
      if (s >= 1) {
        float4 u0, u1;
        const float* pb = pk + (size_t)((s - 1) & 15) * SLOTF + toff;
        poll2(pb, (unsigned)s, u0, u1);
        scat(hA, q0, u0, u1);
      }
    } else {
      if (s >= 2) {
        float4 a0, a1, b0, b1;
        const float* pa = pk + (size_t)((s - 1) & 15) * SLOTF + toff;
        const float* pb = pk + (size_t)(RING + ((s - 2) & 15)) * SLOTF + toff;
        poll4(pa, (unsigned)s, pb, (unsigned)(s - 1), a0, a1, b0, b1);
        scat(hA, q0, a0, a1);
        scat(hB, q0, b0, b1);
      } else if (s == 1) {
        float4 a0, a1;
        const float* pa = pk + (size_t)0 * SLOTF + toff;
        poll2(pa, 1u, a0, a1);
        scat(hA, q0, a0, a1);
      }
    }
    __syncthreads();   // stage visible

    // ---- matvec + reduce ----
    float4 acc[BPG] = {{0,0,0,0},{0,0,0,0},{0,0,0,0},{0,0,0,0}};
    if (s >= 1) {
      if (!isL1) {
        fma_mv_lds(acc, wregB, hA, jg);
      } else {
        fma_mv_lds(acc, wregA, hA, jg);           // W_ih1 * h0_{s-1}
        if (s >= 2) fma_mv_lds(acc, wregB, hB, jg); // + W_hh1 * h1_{s-2}
      }
#pragma unroll
      for (int b = 0; b < BPG; ++b) {
        acc[b].x += __shfl_down(acc[b].x, 32); acc[b].y += __shfl_down(acc[b].y, 32);
        acc[b].z += __shfl_down(acc[b].z, 32); acc[b].w += __shfl_down(acc[b].w, 32);
        acc[b].x += __shfl_down(acc[b].x, 16); acc[b].y += __shfl_down(acc[b].y, 16);
        acc[b].z += __shfl_down(acc[b].z, 16); acc[b].w += __shfl_down(acc[b].w, 16);
      }
      if (wl < 16) {
#pragma unroll
        for (int b = 0; b < BPG; ++b) {
          part[wave][wl][b * 4 + 0] = acc[b].x;
          part[wave][wl][b * 4 + 1] = acc[b].y;
          part[wave][wl][b * 4 + 2] = acc[b].z;
          part[wave][wl][b * 4 + 3] = acc[b].w;
        }
      }
    }
    __syncthreads();   // part visible

    // ---- finalize (waves 0-3): reduce + tanh + LL-packet publish ----
    if (tid < 256) {
      if (!isL1) {
        float v = xv;
        if (s >= 1) {
#pragma unroll
          for (int w = 0; w < 8; ++w) v += part[w][fo >> 2][fbb * 4 + (fo & 3)];
        }
        float h = tanhf(v);
        float* pw = pk + (size_t)(s & 15) * SLOTF + wpo;
        float2 pkt; pkt.x = h; pkt.y = __uint_as_float((unsigned)(s + 1));
        asm volatile("global_store_dwordx2 %0, %1, off sc0 sc1"
                     :: "v"(pw), "v"(pkt) : "memory");
      } else if (s >= 1) {
        float v = bs;
#pragma unroll
        for (int w = 0; w < 8; ++w) v += part[w][fo >> 2][fbb * 4 + (fo & 3)];
        float h = tanhf(v);
        pacc += h;
        float* pw = pk + (size_t)(RING + ((s - 1) & 15)) * SLOTF + wpo;
        float2 pkt; pkt.x = h; pkt.y = __uint_as_float((unsigned)s);
        asm volatile("global_store_dwordx2 %0, %1, off sc0 sc1"
                     :: "v"(pw), "v"(pkt) : "memory");
      }
      // no vmcnt wait: the packet store IS the release
    }

    // ---- periodic full barrier (skew bound: drift < BARK < RING) ----
    if ((s & (BARK - 1)) == (BARK - 1)) {
      unsigned bt = (unsigned)((s >> 3) + 1);
      if (tid == 0) {
        unsigned* fp = flg + role * 32;
        asm volatile("global_store_dword %0, %1, off sc0 sc1"
                     :: "v"(fp), "v"(bt) : "memory");
      }
      if (tid < LBLK) {
        const unsigned* fp = flg + tid * 32;
        unsigned v;
        do {
          asm volatile("global_load_dword %0, %1, off sc0 sc1\n\ts_waitcnt vmcnt(0)"
                       : "=v"(v) : "v"(fp) : "memory");
          if (v < bt) __builtin_amdgcn_s_sleep(2);
        } while (v < bt);
      }
      __syncthreads();
    }
  }

  // ---- L1 epilogue: h1_511 from h0_511 (tag 512) and h1_510 (tag 511) ----
  if (isL1) {
    float4 a0, a1, b0, b1;
    const float* pa = pk + (size_t)15 * SLOTF + toff;
    const float* pb = pk + (size_t)(RING + 14) * SLOTF + toff;
    poll4(pa, (unsigned)SS, pb, (unsigned)(SS - 1), a0, a1, b0, b1);
    scat(hA, q0, a0, a1);
    scat(hB, q0, b0, b1);
    __syncthreads();
    float4 acc[BPG] = {{0,0,0,0},{0,0,0,0},{0,0,0,0},{0,0,0,0}};
    fma_mv_lds(acc, wregA, hA, jg);
    fma_mv_lds(acc, wregB, hB, jg);
#pragma unroll
    for (int b = 0; b < BPG; ++b) {
      acc[b].x += __shfl_down(acc[b].x, 32); acc[b].y += __shfl_down(acc[b].y, 32);
      acc[b].z += __shfl_down(acc[b].z, 32); acc[b].w += __shfl_down(acc[b].w, 32);
      acc[b].x += __shfl_down(acc[b].x, 16); acc[b].y += __shfl_down(acc[b].y, 16);
      acc[b].z += __shfl_down(acc[b].z, 16); acc[b].w += __shfl_down(acc[b].w, 16);
    }
    if (wl < 16) {
#pragma unroll
      for (int b = 0; b < BPG; ++b) {
        part[wave][wl][b * 4 + 0] = acc[b].x;
        part[wave][wl][b * 4 + 1] = acc[b].y;
        part[wave][wl][b * 4 + 2] = acc[b].z;
        part[wave][wl][b * 4 + 3] = acc[b].w;
      }
    }
    __syncthreads();
    if (tid < 256) {
      float v = bs;
#pragma unroll
      for (int w = 0; w < 8; ++w) v += part[w][fo >> 2][fbb * 4 + (fo & 3)];
      pacc += tanhf(v);
      pooled[(size_t)(grp * BPG + fbb) * HH + fog] = pacc * (1.0f / SS);
    }
  }
}

// Final head: out[b][c] = sum_k pooled[b][k] * W_out[c][k] + b_out[c]
__global__ void out_kernel(const float* __restrict__ pooled,
                           const float* __restrict__ W_out,
                           const float* __restrict__ b_out,
                           float* __restrict__ out) {
  int tid = threadIdx.x;
  if (tid >= BB * 2) return;
  int b = tid >> 1, c = tid & 1;
  float acc = b_out[c];
  for (int k = 0; k < HH; ++k)
    acc += pooled[(size_t)b * HH + k] * W_out[(size_t)c * HH + k];
  out[(size_t)b * 2 + c] = acc;
}

extern "C" void kernel_launch(void* const* d_in, const int* in_sizes, int n_in,
                              void* d_out, int out_size, void* d_ws, size_t ws_size,
                              hipStream_t stream) {
  const int*   x     = (const int*)d_in[0];
  const float* emb   = (const float*)d_in[1];
  const float* W_ih0 = (const float*)d_in[2];
  const float* W_hh0 = (const float*)d_in[3];
  const float* b_ih0 = (const float*)d_in[4];
  const float* b_hh0 = (const float*)d_in[5];
  const float* W_ih1 = (const float*)d_in[6];
  const float* W_hh1 = (const float*)d_in[7];
  const float* b_ih1 = (const float*)d_in[8];
  const float* b_hh1 = (const float*)d_in[9];
  const float* W_out = (const float*)d_in[10];
  const float* b_out = (const float*)d_in[11];

  float* ws = (float*)d_ws;
  const size_t NBSH = (size_t)BB * SS * HH;            // 16777216
  const size_t PKF  = (size_t)NGROUPS * GPKF;          // 2,097,152 floats (8MB)
  float* xp      = ws;                    // 64 MB
  float* WThh0   = ws + NBSH;             // 1 MB
  float* WTih1   = WThh0 + HH * HH;       // 1 MB
  float* WThh1   = WTih1 + HH * HH;       // 1 MB
  float* pooled  = WThh1 + HH * HH;       // 128 KB
  float* pkts    = pooled + BB * HH;      // 8 MB
  unsigned* flags = (unsigned*)(pkts + PKF);  // 32 KB

  init_sync<<<8192, 256, 0, stream>>>(pkts, flags);

  dim3 tb(32, 8), tg(16, 16);
  transpose512<<<tg, tb, 0, stream>>>(W_hh0, WThh0);
  transpose512<<<tg, tb, 0, stream>>>(W_ih1, WTih1);
  transpose512<<<tg, tb, 0, stream>>>(W_hh1, WThh1);

  dim3 gg(512, 8);
  xp_gemm<EE, true><<<gg, 256, 0, stream>>>(nullptr, x, emb, W_ih0, b_ih0, b_hh0, xp);
  rec_fused<<<NGROUPS * LBLK, RECT, 0, stream>>>(
      xp, WThh0, WTih1, WThh1, b_ih1, b_hh1, pooled, pkts, flags);
  out_kernel<<<1, 128, 0, stream>>>(pooled, W_out, b_out, (float*)d_out);
}